// Round 1
// baseline (4550.793 us; speedup 1.0000x reference)
//
#include <hip/hip_runtime.h>

#define F_IN 128
#define HID 128
#define C_OUT 64
#define NEG_SLOPE 0.2f

// ---------------------------------------------------------------------------
// v_s1[f] = sum_c W_src1[f][c]*att_src1[c]  (and v_d1, v_s2, v_d2)
// Lets us compute a_src/a_dst as x . v  without materializing h_dst at all.
// ---------------------------------------------------------------------------
__global__ void k_vec(const float* __restrict__ Ws1, const float* __restrict__ Wd1,
                      const float* __restrict__ as1, const float* __restrict__ ad1,
                      const float* __restrict__ Ws2, const float* __restrict__ Wd2,
                      const float* __restrict__ as2, const float* __restrict__ ad2,
                      float* __restrict__ v) {
    int f = threadIdx.x;  // 0..127
    float s1 = 0.f, d1 = 0.f, s2 = 0.f, d2 = 0.f;
    for (int c = 0; c < HID; ++c) {
        s1 += Ws1[f * HID + c] * as1[c];
        d1 += Wd1[f * HID + c] * ad1[c];
    }
    for (int c = 0; c < C_OUT; ++c) {
        s2 += Ws2[f * C_OUT + c] * as2[c];
        d2 += Wd2[f * C_OUT + c] * ad2[c];
    }
    v[f] = s1; v[128 + f] = d1; v[256 + f] = s2; v[384 + f] = d2;
}

// ---------------------------------------------------------------------------
// Init: accum1 rows = b1, out rows = b2, denoms = 0. (ws/out are 0xAA-poisoned
// before every launch, so everything we accumulate into must be seeded here.)
// ---------------------------------------------------------------------------
__global__ void k_init(float* __restrict__ accum1, float* __restrict__ out,
                       float* __restrict__ denom1, float* __restrict__ denom2,
                       const float* __restrict__ b1, const float* __restrict__ b2,
                       int N) {
    long long i = (long long)blockIdx.x * 256 + threadIdx.x;
    long long n128 = (long long)N * 128, n64 = (long long)N * 64;
    if (i < n128) {
        accum1[i] = b1[i & 127];
    } else if (i < n128 + n64) {
        out[i - n128] = b2[(i - n128) & 63];
    } else if (i < n128 + n64 + N) {
        denom1[i - n128 - n64] = 0.f;
    } else if (i < n128 + n64 + 2 * N) {
        denom2[i - n128 - n64 - N] = 0.f;
    }
}

// ---------------------------------------------------------------------------
// Per-row dual dot products: a_s[n] = x[n].vs, a_d[n] = x[n].vd
// One wave per row, float2 per lane (coalesced 512B row read), shfl reduce.
// ---------------------------------------------------------------------------
template <bool RELU>
__global__ void k_rowdots(const float* __restrict__ X, const float* __restrict__ vs,
                          const float* __restrict__ vd, float* __restrict__ a_s,
                          float* __restrict__ a_d, int N) {
    int wave = (int)(((long long)blockIdx.x * blockDim.x + threadIdx.x) >> 6);
    int lane = threadIdx.x & 63;
    if (wave >= N) return;
    float2 xv = ((const float2*)(X + (long long)wave * 128))[lane];
    if (RELU) { xv.x = fmaxf(xv.x, 0.f); xv.y = fmaxf(xv.y, 0.f); }
    float2 vsv = ((const float2*)vs)[lane];
    float2 vdv = ((const float2*)vd)[lane];
    float ds = xv.x * vsv.x + xv.y * vsv.y;
    float dd = xv.x * vdv.x + xv.y * vdv.y;
    #pragma unroll
    for (int off = 32; off; off >>= 1) {
        ds += __shfl_xor(ds, off);
        dd += __shfl_xor(dd, off);
    }
    if (lane == 0) { a_s[wave] = ds; a_d[wave] = dd; }
}

// ---------------------------------------------------------------------------
// H = X @ W  (X: N x 128 row-major, W: 128 x COLS, H: N x COLS)
// Block = COLS threads; each block does ROWS=16 rows. X reads are block-
// uniform -> compiler emits s_load (scalar cache); W reads coalesced, L2-hot.
// ---------------------------------------------------------------------------
template <int COLS, bool RELU>
__global__ void k_gemm(const float* __restrict__ X, const float* __restrict__ W,
                       float* __restrict__ H, int N) {
    const int ROWS = 16;
    int c = threadIdx.x;
    long long row0 = (long long)blockIdx.x * ROWS;
    const float* xb = X + row0 * F_IN;

    if (row0 + ROWS <= N) {
        float acc[ROWS];
        #pragma unroll
        for (int r = 0; r < ROWS; ++r) acc[r] = 0.f;
        #pragma unroll 8
        for (int f = 0; f < F_IN; ++f) {
            float w = W[f * COLS + c];
            #pragma unroll
            for (int r = 0; r < ROWS; ++r) {
                float xv = xb[r * F_IN + f];
                if (RELU) xv = fmaxf(xv, 0.f);
                acc[r] += xv * w;
            }
        }
        #pragma unroll
        for (int r = 0; r < ROWS; ++r)
            H[(row0 + r) * COLS + c] = acc[r];
    } else {
        for (int r = 0; r < ROWS; ++r) {
            if (row0 + r >= N) break;
            float a = 0.f;
            for (int f = 0; f < F_IN; ++f) {
                float xv = xb[r * F_IN + f];
                if (RELU) xv = fmaxf(xv, 0.f);
                a += xv * W[f * COLS + c];
            }
            H[(row0 + r) * COLS + c] = a;
        }
    }
}

// ---------------------------------------------------------------------------
// Per-edge: ee = exp(leaky_relu(a_s[src]+a_d[dst])); denom[dst] += ee.
// No segment-max: logits are O(10) max, exp() is overflow-safe in fp32 and
// alpha = ee/denom is mathematically identical to the max-subtracted form.
// ---------------------------------------------------------------------------
__global__ void k_edge(const int* __restrict__ srcs, const int* __restrict__ dsts,
                       const float* __restrict__ a_s, const float* __restrict__ a_d,
                       float* __restrict__ ee, float* __restrict__ denom, int E) {
    int e = blockIdx.x * 256 + threadIdx.x;
    if (e >= E) return;
    int s = srcs[e], d = dsts[e];
    float t = a_s[s] + a_d[d];
    t = (t > 0.f) ? t : NEG_SLOPE * t;
    float ex = __expf(t);
    ee[e] = ex;
    atomicAdd(denom + d, ex);
}

// ---------------------------------------------------------------------------
// out[dst] += h[src] * (ee/denom[dst]).  C/4 threads per edge, float4 gather,
// 4 fire-and-forget global_atomic_add_f32 per thread.
// ---------------------------------------------------------------------------
template <int C>
__global__ void k_scatter(const int* __restrict__ srcs, const int* __restrict__ dsts,
                          const float* __restrict__ ee, const float* __restrict__ denom,
                          const float* __restrict__ H, float* __restrict__ out, int E) {
    const int TPE = C / 4;  // threads per edge (power of two)
    long long gid = (long long)blockIdx.x * blockDim.x + threadIdx.x;
    long long e = gid / TPE;
    int q = (int)(gid % TPE);
    if (e >= E) return;
    int s = srcs[e], d = dsts[e];
    float alpha = __fdividef(ee[e], denom[d]);
    float4 hv = ((const float4*)(H + (long long)s * C))[q];
    float* op = out + (long long)d * C + q * 4;
    atomicAdd(op + 0, hv.x * alpha);
    atomicAdd(op + 1, hv.y * alpha);
    atomicAdd(op + 2, hv.z * alpha);
    atomicAdd(op + 3, hv.w * alpha);
}

extern "C" void kernel_launch(void* const* d_in, const int* in_sizes, int n_in,
                              void* d_out, int out_size, void* d_ws, size_t ws_size,
                              hipStream_t stream) {
    const float* x   = (const float*)d_in[0];
    const int*   ei  = (const int*)d_in[1];
    const float* Ws1 = (const float*)d_in[2];
    const float* Wd1 = (const float*)d_in[3];
    const float* as1 = (const float*)d_in[4];
    const float* ad1 = (const float*)d_in[5];
    const float* b1  = (const float*)d_in[6];
    const float* Ws2 = (const float*)d_in[7];
    const float* Wd2 = (const float*)d_in[8];
    const float* as2 = (const float*)d_in[9];
    const float* ad2 = (const float*)d_in[10];
    const float* b2  = (const float*)d_in[11];
    float* out = (float*)d_out;

    const int N = in_sizes[0] / F_IN;   // 100000
    const int E = in_sizes[1] / 2;      // 1600000
    const int* srcs = ei;
    const int* dsts = ei + E;

    // Workspace layout (~111 MB). h2 reuses h1's buffer (h1 dead after scatter1).
    float* ws     = (float*)d_ws;
    float* h1     = ws;                         // N*128
    float* h2     = h1;                         // N*64 (reuse)
    float* accum1 = h1 + (size_t)N * 128;       // N*128 (seeded with b1)
    float* a_s1   = accum1 + (size_t)N * 128;   // N
    float* a_d1   = a_s1 + N;
    float* a_s2   = a_d1 + N;
    float* a_d2   = a_s2 + N;
    float* denom1 = a_d2 + N;
    float* denom2 = denom1 + N;
    float* ee     = denom2 + N;                 // E
    float* vecs   = ee + (size_t)E;             // 512

    k_vec<<<1, 128, 0, stream>>>(Ws1, Wd1, as1, ad1, Ws2, Wd2, as2, ad2, vecs);

    long long initN = (long long)N * (F_IN + C_OUT + 2);
    k_init<<<(int)((initN + 255) / 256), 256, 0, stream>>>(accum1, out, denom1, denom2, b1, b2, N);

    int rowdot_blocks = (N + 3) / 4;  // 4 waves (rows) per 256-thread block

    // ---- Layer 1 ----
    k_rowdots<false><<<rowdot_blocks, 256, 0, stream>>>(x, vecs, vecs + 128, a_s1, a_d1, N);
    k_gemm<128, false><<<(N + 15) / 16, 128, 0, stream>>>(x, Ws1, h1, N);
    k_edge<<<(E + 255) / 256, 256, 0, stream>>>(srcs, dsts, a_s1, a_d1, ee, denom1, E);
    {
        long long t = (long long)E * 32;
        k_scatter<128><<<(int)((t + 255) / 256), 256, 0, stream>>>(srcs, dsts, ee, denom1, h1, accum1, E);
    }

    // ---- Layer 2 (input = relu(accum1), bias b1 already inside accum1) ----
    k_rowdots<true><<<rowdot_blocks, 256, 0, stream>>>(accum1, vecs + 256, vecs + 384, a_s2, a_d2, N);
    k_gemm<64, true><<<(N + 15) / 16, 64, 0, stream>>>(accum1, Ws2, h2, N);
    k_edge<<<(E + 255) / 256, 256, 0, stream>>>(srcs, dsts, a_s2, a_d2, ee, denom2, E);
    {
        long long t = (long long)E * 16;
        k_scatter<64><<<(int)((t + 255) / 256), 256, 0, stream>>>(srcs, dsts, ee, denom2, h2, out, E);
    }
}

// Round 2
// 659.264 us; speedup vs baseline: 6.9028x; 6.9028x over previous
//
#include <hip/hip_runtime.h>

#define F_IN 128
#define HID 128
#define C_OUT 64
#define NEG_SLOPE 0.2f
#define SCAN_CHUNK 2048  // 256 threads x 8 elements

// ---------------------------------------------------------------------------
// v_s1[f] = sum_c W_src1[f][c]*att_src1[c]  (and v_d1, v_s2, v_d2)
// a_src = (x@W)@att = x@(W@att): h_dst never materialized.
// ---------------------------------------------------------------------------
__global__ void k_vec(const float* __restrict__ Ws1, const float* __restrict__ Wd1,
                      const float* __restrict__ as1, const float* __restrict__ ad1,
                      const float* __restrict__ Ws2, const float* __restrict__ Wd2,
                      const float* __restrict__ as2, const float* __restrict__ ad2,
                      float* __restrict__ v) {
    int f = threadIdx.x;  // 0..127
    float s1 = 0.f, d1 = 0.f, s2 = 0.f, d2 = 0.f;
    for (int c = 0; c < HID; ++c) {
        s1 += Ws1[f * HID + c] * as1[c];
        d1 += Wd1[f * HID + c] * ad1[c];
    }
    for (int c = 0; c < C_OUT; ++c) {
        s2 += Ws2[f * C_OUT + c] * as2[c];
        d2 += Wd2[f * C_OUT + c] * ad2[c];
    }
    v[f] = s1; v[128 + f] = d1; v[256 + f] = s2; v[384 + f] = d2;
}

// ---------------------------------------------------------------------------
// CSR build: zero counts -> hist (rank = old count) -> 3-phase scan -> place
// ---------------------------------------------------------------------------
__global__ void k_zero(int* __restrict__ cnt, int N) {
    int i = blockIdx.x * 256 + threadIdx.x;
    if (i < N) cnt[i] = 0;
}

__global__ void k_hist(const int* __restrict__ dsts, int* __restrict__ cnt,
                       int* __restrict__ rank, int E) {
    int e = blockIdx.x * 256 + threadIdx.x;
    if (e < E) rank[e] = atomicAdd(&cnt[dsts[e]], 1);
}

__global__ void k_blocksum(const int* __restrict__ cnt, int* __restrict__ bsum, int N) {
    __shared__ int sh[256];
    int t = threadIdx.x;
    long long base = (long long)blockIdx.x * SCAN_CHUNK + (long long)t * 8;
    int s = 0;
    #pragma unroll
    for (int k = 0; k < 8; ++k) {
        long long i = base + k;
        if (i < N) s += cnt[i];
    }
    sh[t] = s;
    __syncthreads();
    for (int off = 128; off; off >>= 1) {
        if (t < off) sh[t] += sh[t + off];
        __syncthreads();
    }
    if (t == 0) bsum[blockIdx.x] = sh[0];
}

__global__ void k_scan_bsum(const int* __restrict__ bsum, int* __restrict__ bpre,
                            int nb, int* __restrict__ rowptr, int N) {
    if (threadIdx.x == 0 && blockIdx.x == 0) {
        int off = 0;
        for (int b = 0; b < nb; ++b) { bpre[b] = off; off += bsum[b]; }
        rowptr[N] = off;  // == E
    }
}

__global__ void k_scan_chunks(const int* __restrict__ cnt, const int* __restrict__ bpre,
                              int* __restrict__ rowptr, int N) {
    __shared__ int sh[256];
    int t = threadIdx.x;
    long long base = (long long)blockIdx.x * SCAN_CHUNK + (long long)t * 8;
    int loc[8];
    int s = 0;
    #pragma unroll
    for (int k = 0; k < 8; ++k) {
        long long i = base + k;
        int v = (i < N) ? cnt[i] : 0;
        loc[k] = s;   // exclusive within thread
        s += v;
    }
    sh[t] = s;
    __syncthreads();
    // Hillis-Steele inclusive scan over thread sums
    for (int off = 1; off < 256; off <<= 1) {
        int tmp = (t >= off) ? sh[t - off] : 0;
        __syncthreads();
        sh[t] += tmp;
        __syncthreads();
    }
    int toff = bpre[blockIdx.x] + sh[t] - s;  // exclusive thread offset + chunk base
    #pragma unroll
    for (int k = 0; k < 8; ++k) {
        long long i = base + k;
        if (i < N) rowptr[i] = toff + loc[k];
    }
}

__global__ void k_place(const int* __restrict__ srcs, const int* __restrict__ dsts,
                        const int* __restrict__ rowptr, const int* __restrict__ rank,
                        int* __restrict__ perm_src, int E) {
    int e = blockIdx.x * 256 + threadIdx.x;
    if (e >= E) return;
    int d = dsts[e];
    perm_src[rowptr[d] + rank[e]] = srcs[e];
}

// ---------------------------------------------------------------------------
// Per-row dual dot products: a_s[n] = x[n].vs, a_d[n] = x[n].vd
// ---------------------------------------------------------------------------
template <bool RELU>
__global__ void k_rowdots(const float* __restrict__ X, const float* __restrict__ vs,
                          const float* __restrict__ vd, float* __restrict__ a_s,
                          float* __restrict__ a_d, int N) {
    int wave = (int)(((long long)blockIdx.x * blockDim.x + threadIdx.x) >> 6);
    int lane = threadIdx.x & 63;
    if (wave >= N) return;
    float2 xv = ((const float2*)(X + (long long)wave * 128))[lane];
    if (RELU) { xv.x = fmaxf(xv.x, 0.f); xv.y = fmaxf(xv.y, 0.f); }
    float2 vsv = ((const float2*)vs)[lane];
    float2 vdv = ((const float2*)vd)[lane];
    float ds = xv.x * vsv.x + xv.y * vsv.y;
    float dd = xv.x * vdv.x + xv.y * vdv.y;
    #pragma unroll
    for (int off = 32; off; off >>= 1) {
        ds += __shfl_xor(ds, off);
        dd += __shfl_xor(dd, off);
    }
    if (lane == 0) { a_s[wave] = ds; a_d[wave] = dd; }
}

// ---------------------------------------------------------------------------
// H = X @ W  (X: N x 128 row-major, W: 128 x COLS, H: N x COLS)
// ---------------------------------------------------------------------------
template <int COLS, bool RELU>
__global__ void k_gemm(const float* __restrict__ X, const float* __restrict__ W,
                       float* __restrict__ H, int N) {
    const int ROWS = 16;
    int c = threadIdx.x;
    long long row0 = (long long)blockIdx.x * ROWS;
    const float* xb = X + row0 * F_IN;

    if (row0 + ROWS <= N) {
        float acc[ROWS];
        #pragma unroll
        for (int r = 0; r < ROWS; ++r) acc[r] = 0.f;
        #pragma unroll 8
        for (int f = 0; f < F_IN; ++f) {
            float w = W[f * COLS + c];
            #pragma unroll
            for (int r = 0; r < ROWS; ++r) {
                float xv = xb[r * F_IN + f];
                if (RELU) xv = fmaxf(xv, 0.f);
                acc[r] += xv * w;
            }
        }
        #pragma unroll
        for (int r = 0; r < ROWS; ++r)
            H[(row0 + r) * COLS + c] = acc[r];
    } else {
        for (int r = 0; r < ROWS; ++r) {
            if (row0 + r >= N) break;
            float a = 0.f;
            for (int f = 0; f < F_IN; ++f) {
                float xv = xb[r * F_IN + f];
                if (RELU) xv = fmaxf(xv, 0.f);
                a += xv * W[f * COLS + c];
            }
            H[(row0 + r) * COLS + c] = a;
        }
    }
}

// ---------------------------------------------------------------------------
// Fused softmax + aggregate, one wave per dst node, zero atomics.
// out[d] = (sum_j exp(lrelu(a_s[s_j]+a_d[d])) * H[s_j]) / sum_j exp(...) + bias
// No segment-max needed: logits are O(10), exp() safe in fp32, alpha identical.
// ---------------------------------------------------------------------------
template <int C>
__global__ void k_agg(const int* __restrict__ rowptr, const int* __restrict__ perm_src,
                      const float* __restrict__ a_s, const float* __restrict__ a_d,
                      const float* __restrict__ H, const float* __restrict__ bias,
                      float* __restrict__ out, int N) {
    constexpr int VPL = C / 64;  // floats per lane: 2 (C=128) or 1 (C=64)
    int wave = (int)(((long long)blockIdx.x * blockDim.x + threadIdx.x) >> 6);
    int lane = threadIdx.x & 63;
    if (wave >= N) return;
    int beg = rowptr[wave], end = rowptr[wave + 1];
    float ad = a_d[wave];
    float acc[VPL];
    #pragma unroll
    for (int k = 0; k < VPL; ++k) acc[k] = 0.f;
    float wsum = 0.f;

    int i = beg;
    for (; i + 2 <= end; i += 2) {  // 2-edge unroll: 2 gathers in flight
        int s0 = perm_src[i], s1 = perm_src[i + 1];
        float t0 = a_s[s0] + ad, t1 = a_s[s1] + ad;
        t0 = (t0 > 0.f) ? t0 : NEG_SLOPE * t0;
        t1 = (t1 > 0.f) ? t1 : NEG_SLOPE * t1;
        float e0 = __expf(t0), e1 = __expf(t1);
        const float* h0 = H + (long long)s0 * C + lane * VPL;
        const float* h1 = H + (long long)s1 * C + lane * VPL;
        #pragma unroll
        for (int k = 0; k < VPL; ++k) acc[k] += e0 * h0[k];
        #pragma unroll
        for (int k = 0; k < VPL; ++k) acc[k] += e1 * h1[k];
        wsum += e0 + e1;
    }
    if (i < end) {
        int s = perm_src[i];
        float t = a_s[s] + ad;
        t = (t > 0.f) ? t : NEG_SLOPE * t;
        float ee = __expf(t);
        const float* hp = H + (long long)s * C + lane * VPL;
        #pragma unroll
        for (int k = 0; k < VPL; ++k) acc[k] += ee * hp[k];
        wsum += ee;
    }

    float inv = (wsum > 0.f) ? __fdividef(1.f, wsum) : 0.f;  // deg-0 -> bias only
    float* op = out + (long long)wave * C + lane * VPL;
    const float* bp = bias + lane * VPL;
    #pragma unroll
    for (int k = 0; k < VPL; ++k) op[k] = acc[k] * inv + bp[k];
}

extern "C" void kernel_launch(void* const* d_in, const int* in_sizes, int n_in,
                              void* d_out, int out_size, void* d_ws, size_t ws_size,
                              hipStream_t stream) {
    const float* x   = (const float*)d_in[0];
    const int*   ei  = (const int*)d_in[1];
    const float* Ws1 = (const float*)d_in[2];
    const float* as1 = (const float*)d_in[4];
    const float* ad1 = (const float*)d_in[5];
    const float* b1  = (const float*)d_in[6];
    const float* Ws2 = (const float*)d_in[7];
    const float* as2 = (const float*)d_in[9];
    const float* ad2 = (const float*)d_in[10];
    const float* b2  = (const float*)d_in[11];
    const float* Wd1 = (const float*)d_in[3];
    const float* Wd2 = (const float*)d_in[8];
    float* out = (float*)d_out;

    const int N = in_sizes[0] / F_IN;   // 100000
    const int E = in_sizes[1] / 2;      // 1600000
    const int* srcs = ei;
    const int* dsts = ei + E;

    // Workspace (~111 MB). rank aliases h1 (dead before gemm writes h1);
    // h2 aliases h1 (h1 dead after layer-1 agg).
    float* ws     = (float*)d_ws;
    float* h1     = ws;                            // N*128 floats
    float* h2     = h1;                            // N*64 (reuse)
    int*   rank   = (int*)h1;                      // E ints (aliases h1)
    float* accum1 = h1 + (size_t)N * 128;          // N*128
    float* a_s1   = accum1 + (size_t)N * 128;      // N
    float* a_d1   = a_s1 + N;
    float* a_s2   = a_d1 + N;
    float* a_d2   = a_s2 + N;
    int*   cnt    = (int*)(a_d2 + N);              // N
    int*   rowptr = cnt + N;                       // N+1
    int*   bsum   = rowptr + N + 1;                // 64
    int*   bpre   = bsum + 64;                     // 64
    int*   perm   = bpre + 64;                     // E
    float* vecs   = (float*)(perm + E);            // 512

    const int nb = (N + SCAN_CHUNK - 1) / SCAN_CHUNK;

    k_vec<<<1, 128, 0, stream>>>(Ws1, Wd1, as1, ad1, Ws2, Wd2, as2, ad2, vecs);

    // ---- CSR build (once, reused by both layers) ----
    k_zero<<<(N + 255) / 256, 256, 0, stream>>>(cnt, N);
    k_hist<<<(E + 255) / 256, 256, 0, stream>>>(dsts, cnt, rank, E);
    k_blocksum<<<nb, 256, 0, stream>>>(cnt, bsum, N);
    k_scan_bsum<<<1, 64, 0, stream>>>(bsum, bpre, nb, rowptr, N);
    k_scan_chunks<<<nb, 256, 0, stream>>>(cnt, bpre, rowptr, N);
    k_place<<<(E + 255) / 256, 256, 0, stream>>>(srcs, dsts, rowptr, rank, perm, E);

    int rowdot_blocks = (N + 3) / 4;  // 4 waves per 256-thread block

    // ---- Layer 1 ----
    k_rowdots<false><<<rowdot_blocks, 256, 0, stream>>>(x, vecs, vecs + 128, a_s1, a_d1, N);
    k_gemm<128, false><<<(N + 15) / 16, 128, 0, stream>>>(x, Ws1, h1, N);
    k_agg<128><<<(N + 3) / 4, 256, 0, stream>>>(rowptr, perm, a_s1, a_d1, h1, b1, accum1, N);

    // ---- Layer 2 (input = relu(accum1), b1 already inside accum1) ----
    k_rowdots<true><<<rowdot_blocks, 256, 0, stream>>>(accum1, vecs + 256, vecs + 384, a_s2, a_d2, N);
    k_gemm<64, true><<<(N + 15) / 16, 64, 0, stream>>>(accum1, Ws2, h2, N);
    k_agg<64><<<(N + 3) / 4, 256, 0, stream>>>(rowptr, perm, a_s2, a_d2, h2, b2, out, N);
}

// Round 4
// 483.210 us; speedup vs baseline: 9.4178x; 1.3643x over previous
//
#include <hip/hip_runtime.h>

#define F_IN 128
#define NEG_SLOPE 0.2f
#define SCAN_CHUNK 2048  // 256 threads x 8 elements

__device__ inline unsigned short f2bf(float f) {  // fp32 -> bf16 RNE
    unsigned int u = __float_as_uint(f);
    unsigned int r = (u + 0x7fffu + ((u >> 16) & 1u)) >> 16;
    return (unsigned short)r;
}
__device__ inline float bflo(unsigned int u) { return __uint_as_float(u << 16); }
__device__ inline float bfhi(unsigned int u) { return __uint_as_float(u & 0xffff0000u); }

// ---------------------------------------------------------------------------
// Fused: zero the CSR counters (grid covers N) + block 0 computes the four
// projected attention vectors v = W @ att (a_src = x.(W@att), h_dst never
// materialized).
// ---------------------------------------------------------------------------
__global__ void k_vec_zero(const float* __restrict__ Ws1, const float* __restrict__ Wd1,
                           const float* __restrict__ as1, const float* __restrict__ ad1,
                           const float* __restrict__ Ws2, const float* __restrict__ Wd2,
                           const float* __restrict__ as2, const float* __restrict__ ad2,
                           float* __restrict__ v, int* __restrict__ cnt, int N) {
    int i = blockIdx.x * 256 + threadIdx.x;
    if (i < N) cnt[i] = 0;
    if (blockIdx.x == 0 && threadIdx.x < 128) {
        int f = threadIdx.x;
        float s1 = 0.f, d1 = 0.f, s2 = 0.f, d2 = 0.f;
        for (int c = 0; c < 128; ++c) {
            s1 += Ws1[f * 128 + c] * as1[c];
            d1 += Wd1[f * 128 + c] * ad1[c];
        }
        for (int c = 0; c < 64; ++c) {
            s2 += Ws2[f * 64 + c] * as2[c];
            d2 += Wd2[f * 64 + c] * ad2[c];
        }
        v[f] = s1; v[128 + f] = d1; v[256 + f] = s2; v[384 + f] = d2;
    }
}

// ---------------------------------------------------------------------------
// CSR build: hist (rank = old count) -> 3-phase scan -> place (src,dst) pairs
// ---------------------------------------------------------------------------
__global__ void k_hist(const int* __restrict__ dsts, int* __restrict__ cnt,
                       int* __restrict__ rank, int E) {
    int e = blockIdx.x * 256 + threadIdx.x;
    if (e < E) rank[e] = atomicAdd(&cnt[dsts[e]], 1);
}

__global__ void k_blocksum(const int* __restrict__ cnt, int* __restrict__ bsum, int N) {
    __shared__ int sh[256];
    int t = threadIdx.x;
    long long base = (long long)blockIdx.x * SCAN_CHUNK + (long long)t * 8;
    int s = 0;
    #pragma unroll
    for (int k = 0; k < 8; ++k) {
        long long i = base + k;
        if (i < N) s += cnt[i];
    }
    sh[t] = s;
    __syncthreads();
    for (int off = 128; off; off >>= 1) {
        if (t < off) sh[t] += sh[t + off];
        __syncthreads();
    }
    if (t == 0) bsum[blockIdx.x] = sh[0];
}

__global__ void k_scan_bsum(const int* __restrict__ bsum, int* __restrict__ bpre,
                            int nb, int* __restrict__ rowptr, int N) {
    if (threadIdx.x == 0 && blockIdx.x == 0) {
        int off = 0;
        for (int b = 0; b < nb; ++b) { bpre[b] = off; off += bsum[b]; }
        rowptr[N] = off;  // == E
    }
}

__global__ void k_scan_chunks(const int* __restrict__ cnt, const int* __restrict__ bpre,
                              int* __restrict__ rowptr, int N) {
    __shared__ int sh[256];
    int t = threadIdx.x;
    long long base = (long long)blockIdx.x * SCAN_CHUNK + (long long)t * 8;
    int loc[8];
    int s = 0;
    #pragma unroll
    for (int k = 0; k < 8; ++k) {
        long long i = base + k;
        int v = (i < N) ? cnt[i] : 0;
        loc[k] = s;
        s += v;
    }
    sh[t] = s;
    __syncthreads();
    for (int off = 1; off < 256; off <<= 1) {
        int tmp = (t >= off) ? sh[t - off] : 0;
        __syncthreads();
        sh[t] += tmp;
        __syncthreads();
    }
    int toff = bpre[blockIdx.x] + sh[t] - s;
    #pragma unroll
    for (int k = 0; k < 8; ++k) {
        long long i = base + k;
        if (i < N) rowptr[i] = toff + loc[k];
    }
}

__global__ void k_place(const int* __restrict__ srcs, const int* __restrict__ dsts,
                        const int* __restrict__ rowptr, const int* __restrict__ rank,
                        int2* __restrict__ perm_pair, int E) {
    int e = blockIdx.x * 256 + threadIdx.x;
    if (e >= E) return;
    int d = dsts[e];
    perm_pair[rowptr[d] + rank[e]] = make_int2(srcs[e], d);
}

// ---------------------------------------------------------------------------
// Per-edge (CSR order): epack[i] = {src, exp(leaky_relu(a_s[src]+a_d[dst]))}
// No segment-max: logits O(10), fp32 exp overflow-safe, alpha identical.
// ---------------------------------------------------------------------------
__global__ void k_ee(const int2* __restrict__ perm_pair, const float* __restrict__ a_s,
                     const float* __restrict__ a_d, int2* __restrict__ epack, int E) {
    int i = blockIdx.x * 256 + threadIdx.x;
    if (i >= E) return;
    int2 p = perm_pair[i];
    float t = a_s[p.x] + a_d[p.y];
    t = (t > 0.f) ? t : NEG_SLOPE * t;
    epack[i] = make_int2(p.x, __float_as_int(__expf(t)));
}

// ---------------------------------------------------------------------------
// H(bf16) = X @ W, fused with a_s = X.vs, a_d = X.vd (computed from the
// staged registers during LDS fill; 32-lane shfl reduce).
// Block: 256 threads, ROWS x COLS tile, 4x4 register tile per thread.
// ---------------------------------------------------------------------------
template <int COLS, bool RELU>
__launch_bounds__(256)
__global__ void k_gemm(const float* __restrict__ X, const float* __restrict__ W,
                       const float* __restrict__ vs, const float* __restrict__ vd,
                       unsigned short* __restrict__ H, float* __restrict__ a_s,
                       float* __restrict__ a_d, int N) {
    constexpr int CG = COLS / 4;    // col groups: 32 / 16
    constexpr int RG = 256 / CG;    // row groups: 8 / 16
    constexpr int ROWS = RG * 4;    // 32 / 64
    constexpr int K = ROWS / 8;     // float4 staging loads per thread: 4 / 8
    __shared__ float Xs[ROWS * F_IN];
    int tid = threadIdx.x;
    long long row0 = (long long)blockIdx.x * ROWS;

    // ---- stage X tile + rowdot partials from the same registers ----
    float ps[K], pd[K];
    const float4* vs4 = (const float4*)vs;
    const float4* vd4 = (const float4*)vd;
    #pragma unroll
    for (int k = 0; k < K; ++k) {
        int v = tid + 256 * k;
        int r = v >> 5, fq = v & 31;
        float4 val = make_float4(0.f, 0.f, 0.f, 0.f);
        if (row0 + r < N)
            val = ((const float4*)(X + (row0 + r) * (long long)F_IN))[fq];
        if (RELU) {
            val.x = fmaxf(val.x, 0.f); val.y = fmaxf(val.y, 0.f);
            val.z = fmaxf(val.z, 0.f); val.w = fmaxf(val.w, 0.f);
        }
        ((float4*)Xs)[v] = val;
        float4 a = vs4[fq], b = vd4[fq];
        ps[k] = val.x * a.x + val.y * a.y + val.z * a.z + val.w * a.w;
        pd[k] = val.x * b.x + val.y * b.y + val.z * b.z + val.w * b.w;
    }
    // reduce over the 32 lanes holding one row's f-segments
    #pragma unroll
    for (int off = 1; off < 32; off <<= 1) {
        #pragma unroll
        for (int k = 0; k < K; ++k) {
            ps[k] += __shfl_xor(ps[k], off);
            pd[k] += __shfl_xor(pd[k], off);
        }
    }
    if ((tid & 31) == 0) {
        #pragma unroll
        for (int k = 0; k < K; ++k) {
            long long gr = row0 + (tid >> 5) + 8 * k;
            if (gr < N) { a_s[gr] = ps[k]; a_d[gr] = pd[k]; }
        }
    }
    __syncthreads();

    // ---- 4x4 register-tile GEMM ----
    int cg = tid % CG, rg = tid / CG;
    int c0 = cg * 4, r0 = rg * 4;
    float acc[4][4];
    #pragma unroll
    for (int j = 0; j < 4; ++j)
        #pragma unroll
        for (int c = 0; c < 4; ++c) acc[j][c] = 0.f;

    const float* Wp = W + c0;
    for (int f = 0; f < F_IN; f += 4) {
        float4 w0 = *(const float4*)(Wp + (long long)(f + 0) * COLS);
        float4 w1 = *(const float4*)(Wp + (long long)(f + 1) * COLS);
        float4 w2 = *(const float4*)(Wp + (long long)(f + 2) * COLS);
        float4 w3 = *(const float4*)(Wp + (long long)(f + 3) * COLS);
        #pragma unroll
        for (int j = 0; j < 4; ++j) {
            float4 xr = *(const float4*)(Xs + (r0 + j) * F_IN + f);
            acc[j][0] += xr.x * w0.x + xr.y * w1.x + xr.z * w2.x + xr.w * w3.x;
            acc[j][1] += xr.x * w0.y + xr.y * w1.y + xr.z * w2.y + xr.w * w3.y;
            acc[j][2] += xr.x * w0.z + xr.y * w1.z + xr.z * w2.z + xr.w * w3.z;
            acc[j][3] += xr.x * w0.w + xr.y * w1.w + xr.z * w2.w + xr.w * w3.w;
        }
    }

    #pragma unroll
    for (int j = 0; j < 4; ++j) {
        long long gr = row0 + r0 + j;
        if (gr < N) {
            unsigned int lo = (unsigned int)f2bf(acc[j][0]) |
                              ((unsigned int)f2bf(acc[j][1]) << 16);
            unsigned int hi = (unsigned int)f2bf(acc[j][2]) |
                              ((unsigned int)f2bf(acc[j][3]) << 16);
            *(uint2*)(H + gr * COLS + c0) = make_uint2(lo, hi);
        }
    }
}

// ---------------------------------------------------------------------------
// Fused softmax + aggregate, one wave per dst node, zero atomics.
// out[d] = (sum_i ee_i * H[src_i]) / sum_i ee_i + bias   (deg-0 -> bias)
// H is bf16; one 8 B broadcast (src,ee) + one row load per edge, 4-deep unroll.
// ---------------------------------------------------------------------------
template <int C>
__launch_bounds__(256)
__global__ void k_agg(const int* __restrict__ rowptr, const int2* __restrict__ ep,
                      const unsigned short* __restrict__ H, const float* __restrict__ bias,
                      float* __restrict__ out, int N) {
    int wave = (int)(((long long)blockIdx.x * 256 + threadIdx.x) >> 6);
    int lane = threadIdx.x & 63;
    if (wave >= N) return;
    int beg = rowptr[wave], end = rowptr[wave + 1];
    float wsum = 0.f;

    if constexpr (C == 128) {
        const unsigned int* H32 = (const unsigned int*)H;  // 64 uints per row
        float acc0 = 0.f, acc1 = 0.f;
        int i = beg;
        for (; i + 4 <= end; i += 4) {
            int2 e0 = ep[i], e1 = ep[i + 1], e2 = ep[i + 2], e3 = ep[i + 3];
            unsigned int v0 = H32[(long long)e0.x * 64 + lane];
            unsigned int v1 = H32[(long long)e1.x * 64 + lane];
            unsigned int v2 = H32[(long long)e2.x * 64 + lane];
            unsigned int v3 = H32[(long long)e3.x * 64 + lane];
            float w0 = __int_as_float(e0.y), w1 = __int_as_float(e1.y);
            float w2 = __int_as_float(e2.y), w3 = __int_as_float(e3.y);
            acc0 += w0 * bflo(v0) + w1 * bflo(v1) + w2 * bflo(v2) + w3 * bflo(v3);
            acc1 += w0 * bfhi(v0) + w1 * bfhi(v1) + w2 * bfhi(v2) + w3 * bfhi(v3);
            wsum += w0 + w1 + w2 + w3;
        }
        for (; i < end; ++i) {
            int2 e = ep[i];
            unsigned int v = H32[(long long)e.x * 64 + lane];
            float w = __int_as_float(e.y);
            acc0 += w * bflo(v); acc1 += w * bfhi(v);
            wsum += w;
        }
        float inv = (wsum > 0.f) ? __fdividef(1.f, wsum) : 0.f;
        float2 o;
        o.x = acc0 * inv + bias[2 * lane];
        o.y = acc1 * inv + bias[2 * lane + 1];
        *(float2*)(out + (long long)wave * 128 + 2 * lane) = o;
    } else {  // C == 64: one bf16 (ushort) per lane
        float acc = 0.f;
        int i = beg;
        for (; i + 4 <= end; i += 4) {
            int2 e0 = ep[i], e1 = ep[i + 1], e2 = ep[i + 2], e3 = ep[i + 3];
            unsigned int v0 = H[(long long)e0.x * 64 + lane];
            unsigned int v1 = H[(long long)e1.x * 64 + lane];
            unsigned int v2 = H[(long long)e2.x * 64 + lane];
            unsigned int v3 = H[(long long)e3.x * 64 + lane];
            float w0 = __int_as_float(e0.y), w1 = __int_as_float(e1.y);
            float w2 = __int_as_float(e2.y), w3 = __int_as_float(e3.y);
            acc += w0 * bflo(v0) + w1 * bflo(v1) + w2 * bflo(v2) + w3 * bflo(v3);
            wsum += w0 + w1 + w2 + w3;
        }
        for (; i < end; ++i) {
            int2 e = ep[i];
            unsigned int v = H[(long long)e.x * 64 + lane];
            float w = __int_as_float(e.y);
            acc += w * bflo(v);
            wsum += w;
        }
        float inv = (wsum > 0.f) ? __fdividef(1.f, wsum) : 0.f;
        out[(long long)wave * 64 + lane] = acc * inv + bias[lane];
    }
}

extern "C" void kernel_launch(void* const* d_in, const int* in_sizes, int n_in,
                              void* d_out, int out_size, void* d_ws, size_t ws_size,
                              hipStream_t stream) {
    const float* x   = (const float*)d_in[0];
    const int*   ei  = (const int*)d_in[1];
    const float* Ws1 = (const float*)d_in[2];
    const float* Wd1 = (const float*)d_in[3];
    const float* as1 = (const float*)d_in[4];
    const float* ad1 = (const float*)d_in[5];
    const float* b1  = (const float*)d_in[6];
    const float* Ws2 = (const float*)d_in[7];
    const float* Wd2 = (const float*)d_in[8];
    const float* as2 = (const float*)d_in[9];
    const float* ad2 = (const float*)d_in[10];
    const float* b2  = (const float*)d_in[11];
    float* out = (float*)d_out;

    const int N = in_sizes[0] / F_IN;   // 100000
    const int E = in_sizes[1] / 2;      // 1600000
    const int* srcs = ei;
    const int* dsts = ei + E;

    // Workspace (~105 MB). rank aliases accum1 (dead until k_agg<128> writes it).
    unsigned short* hbuf = (unsigned short*)d_ws;              // N*128 bf16
    float* accum1  = (float*)(hbuf + (size_t)N * 128);         // N*128 fp32
    int2*  perm    = (int2*)(accum1 + (size_t)N * 128);        // E (src,dst)
    int2*  epack   = perm + E;                                 // E (src,ee)
    float* a_s1    = (float*)(epack + E);
    float* a_d1    = a_s1 + N;
    float* a_s2    = a_d1 + N;
    float* a_d2    = a_s2 + N;
    int*   cnt     = (int*)(a_d2 + N);                         // N
    int*   rowptr  = cnt + N;                                  // N+1 (+pad)
    int*   bsum    = rowptr + N + 2;                           // 64
    int*   bpre    = bsum + 64;                                // 64
    float* vecs    = (float*)(bpre + 64);                      // 512
    int*   rank    = (int*)accum1;                             // E (alias)

    const int nb = (N + SCAN_CHUNK - 1) / SCAN_CHUNK;

    // ---- vectors + CSR build (reused by both layers) ----
    k_vec_zero<<<(N + 255) / 256, 256, 0, stream>>>(Ws1, Wd1, as1, ad1, Ws2, Wd2,
                                                    as2, ad2, vecs, cnt, N);
    k_hist<<<(E + 255) / 256, 256, 0, stream>>>(dsts, cnt, rank, E);
    k_blocksum<<<nb, 256, 0, stream>>>(cnt, bsum, N);
    k_scan_bsum<<<1, 64, 0, stream>>>(bsum, bpre, nb, rowptr, N);
    k_scan_chunks<<<nb, 256, 0, stream>>>(cnt, bpre, rowptr, N);
    k_place<<<(E + 255) / 256, 256, 0, stream>>>(srcs, dsts, rowptr, rank, perm, E);

    // ---- Layer 1 ----
    k_gemm<128, false><<<(N + 31) / 32, 256, 0, stream>>>(x, Ws1, vecs, vecs + 128,
                                                          hbuf, a_s1, a_d1, N);
    k_ee<<<(E + 255) / 256, 256, 0, stream>>>(perm, a_s1, a_d1, epack, E);
    k_agg<128><<<(N + 3) / 4, 256, 0, stream>>>(rowptr, epack, hbuf, b1, accum1, N);

    // ---- Layer 2 (input = relu(accum1), b1 already inside accum1) ----
    k_gemm<64, true><<<(N + 63) / 64, 256, 0, stream>>>(accum1, Ws2, vecs + 256,
                                                        vecs + 384, hbuf, a_s2, a_d2, N);
    k_ee<<<(E + 255) / 256, 256, 0, stream>>>(perm, a_s2, a_d2, epack, E);
    k_agg<64><<<(N + 3) / 4, 256, 0, stream>>>(rowptr, epack, hbuf, b2, out, N);
}

// Round 5
// 456.134 us; speedup vs baseline: 9.9769x; 1.0594x over previous
//
#include <hip/hip_runtime.h>

#define F_IN 128
#define NEG_SLOPE 0.2f
#define SCAN_CHUNK 2048  // 256 threads x 8 elements

typedef __attribute__((ext_vector_type(8))) short bf16x8;
typedef __attribute__((ext_vector_type(4))) float f32x4;

__device__ inline unsigned short f2bf(float f) {  // fp32 -> bf16 RNE
    unsigned int u = __float_as_uint(f);
    unsigned int r = (u + 0x7fffu + ((u >> 16) & 1u)) >> 16;
    return (unsigned short)r;
}
__device__ inline float bf2f(unsigned short h) { return __uint_as_float((unsigned int)h << 16); }
__device__ inline float bflo(unsigned int u) { return __uint_as_float(u << 16); }
__device__ inline float bfhi(unsigned int u) { return __uint_as_float(u & 0xffff0000u); }

// ---------------------------------------------------------------------------
// Prep (one kernel): zero CSR counters; block 0 computes the 4 projected
// attention vectors v = W@att; blocks 1..96 transpose W1/W2 into bf16 hi/lo
// Wt[n][k] (the MFMA B-operand wants B[k][n] with 8 consecutive k per lane).
// ---------------------------------------------------------------------------
__global__ void k_prep(const float* __restrict__ Ws1, const float* __restrict__ Wd1,
                       const float* __restrict__ as1, const float* __restrict__ ad1,
                       const float* __restrict__ Ws2, const float* __restrict__ Wd2,
                       const float* __restrict__ as2, const float* __restrict__ ad2,
                       float* __restrict__ vecs, int* __restrict__ cnt,
                       unsigned short* __restrict__ w1hi, unsigned short* __restrict__ w1lo,
                       unsigned short* __restrict__ w2hi, unsigned short* __restrict__ w2lo,
                       int N) {
    int bid = blockIdx.x, tid = threadIdx.x;
    int i = bid * 256 + tid;
    if (i < N) cnt[i] = 0;
    if (bid == 0 && tid < 128) {
        int f = tid;
        float s1 = 0.f, d1 = 0.f, s2 = 0.f, d2 = 0.f;
        for (int c = 0; c < 128; ++c) {
            s1 += Ws1[f * 128 + c] * as1[c];
            d1 += Wd1[f * 128 + c] * ad1[c];
        }
        for (int c = 0; c < 64; ++c) {
            s2 += Ws2[f * 64 + c] * as2[c];
            d2 += Wd2[f * 64 + c] * ad2[c];
        }
        vecs[f] = s1; vecs[128 + f] = d1; vecs[256 + f] = s2; vecs[384 + f] = d2;
    } else if (bid >= 1 && bid < 65) {          // W1: 128n x 128k
        int idx = (bid - 1) * 256 + tid;        // < 16384
        int n = idx >> 7, k = idx & 127;
        float w = Ws1[k * 128 + n];
        unsigned short h = f2bf(w);
        w1hi[idx] = h;
        w1lo[idx] = f2bf(w - bf2f(h));
    } else if (bid >= 65 && bid < 97) {         // W2: 64n x 128k
        int idx = (bid - 65) * 256 + tid;       // < 8192
        int n = idx >> 7, k = idx & 127;
        float w = Ws2[k * 64 + n];
        unsigned short h = f2bf(w);
        w2hi[idx] = h;
        w2lo[idx] = f2bf(w - bf2f(h));
    }
}

// ---------------------------------------------------------------------------
// CSR build: hist (rank = old count) -> 3-phase scan -> place (src only)
// ---------------------------------------------------------------------------
__global__ void k_hist(const int* __restrict__ dsts, int* __restrict__ cnt,
                       int* __restrict__ rank, int E) {
    int e = blockIdx.x * 256 + threadIdx.x;
    if (e < E) rank[e] = atomicAdd(&cnt[dsts[e]], 1);
}

__global__ void k_blocksum(const int* __restrict__ cnt, int* __restrict__ bsum, int N) {
    __shared__ int sh[256];
    int t = threadIdx.x;
    long long base = (long long)blockIdx.x * SCAN_CHUNK + (long long)t * 8;
    int s = 0;
    #pragma unroll
    for (int k = 0; k < 8; ++k) {
        long long i = base + k;
        if (i < N) s += cnt[i];
    }
    sh[t] = s;
    __syncthreads();
    for (int off = 128; off; off >>= 1) {
        if (t < off) sh[t] += sh[t + off];
        __syncthreads();
    }
    if (t == 0) bsum[blockIdx.x] = sh[0];
}

__global__ void k_scan_bsum(const int* __restrict__ bsum, int* __restrict__ bpre,
                            int nb, int* __restrict__ rowptr, int N) {
    if (threadIdx.x == 0 && blockIdx.x == 0) {
        int off = 0;
        for (int b = 0; b < nb; ++b) { bpre[b] = off; off += bsum[b]; }
        rowptr[N] = off;  // == E
    }
}

__global__ void k_scan_chunks(const int* __restrict__ cnt, const int* __restrict__ bpre,
                              int* __restrict__ rowptr, int N) {
    __shared__ int sh[256];
    int t = threadIdx.x;
    long long base = (long long)blockIdx.x * SCAN_CHUNK + (long long)t * 8;
    int loc[8];
    int s = 0;
    #pragma unroll
    for (int k = 0; k < 8; ++k) {
        long long i = base + k;
        int v = (i < N) ? cnt[i] : 0;
        loc[k] = s;
        s += v;
    }
    sh[t] = s;
    __syncthreads();
    for (int off = 1; off < 256; off <<= 1) {
        int tmp = (t >= off) ? sh[t - off] : 0;
        __syncthreads();
        sh[t] += tmp;
        __syncthreads();
    }
    int toff = bpre[blockIdx.x] + sh[t] - s;
    #pragma unroll
    for (int k = 0; k < 8; ++k) {
        long long i = base + k;
        if (i < N) rowptr[i] = toff + loc[k];
    }
}

__global__ void k_place(const int* __restrict__ srcs, const int* __restrict__ dsts,
                        const int* __restrict__ rowptr, const int* __restrict__ rank,
                        int* __restrict__ perm_src, int E) {
    int e = blockIdx.x * 256 + threadIdx.x;
    if (e >= E) return;
    perm_src[rowptr[dsts[e]] + rank[e]] = srcs[e];
}

// ---------------------------------------------------------------------------
// MFMA GEMM: H(bf16)[N][COLS] = X[N][128] @ W[128][COLS], fused rowdots
// (a_s = X.vs, a_d = X.vd).  mfma_f32_16x16x32_bf16:
//   A[m=lane&15][k=quad*8+j], B[k=quad*8+j][n=lane&15],
//   D[row=quad*4+reg][col=lane&15]   (verified layouts, learn_hip m89/m120)
// Layer 1 (ABF16=false): X fp32, split into bf16 hi+lo -> 3 MFMAs (~fp32 acc).
// Layer 2 (ABF16=true):  X already bf16 -> 2 MFMAs (B hi+lo).
// Block = 256 thr = 4 waves; wave does 16 rows x COLS; block 64 rows.
// ---------------------------------------------------------------------------
template <int COLS, bool ABF16>
__launch_bounds__(256)
__global__ void k_gemm_mfma(const void* __restrict__ Xv,
                            const unsigned short* __restrict__ Bh,
                            const unsigned short* __restrict__ Bl,
                            const float* __restrict__ vecs_s,
                            const float* __restrict__ vecs_d,
                            unsigned short* __restrict__ H,
                            float* __restrict__ a_s, float* __restrict__ a_d, int N) {
    int tid = threadIdx.x;
    int wave = tid >> 6, lane = tid & 63;
    int q = lane >> 4, rlo = lane & 15;
    long long wrow0 = (long long)blockIdx.x * 64 + wave * 16;
    long long r = wrow0 + rlo;
    long long rr = (r < N) ? r : (long long)(N - 1);  // clamp loads; guard stores

    bf16x8 Ahi[4], Alo[4];
    float ps = 0.f, pd = 0.f;
    #pragma unroll
    for (int kk = 0; kk < 4; ++kk) {
        int k0 = kk * 32 + q * 8;
        float xv[8];
        if constexpr (ABF16) {
            const unsigned short* Xu = (const unsigned short*)Xv;
            bf16x8 av = *(const bf16x8*)(Xu + rr * 128 + k0);
            Ahi[kk] = av;
            #pragma unroll
            for (int j = 0; j < 8; ++j) xv[j] = bf2f((unsigned short)av[j]);
        } else {
            const float* Xf = (const float*)Xv;
            float4 x0 = *(const float4*)(Xf + rr * 128 + k0);
            float4 x1 = *(const float4*)(Xf + rr * 128 + k0 + 4);
            xv[0] = x0.x; xv[1] = x0.y; xv[2] = x0.z; xv[3] = x0.w;
            xv[4] = x1.x; xv[5] = x1.y; xv[6] = x1.z; xv[7] = x1.w;
            bf16x8 ah, al;
            #pragma unroll
            for (int j = 0; j < 8; ++j) {
                unsigned short h = f2bf(xv[j]);
                ah[j] = (short)h;
                al[j] = (short)f2bf(xv[j] - bf2f(h));
            }
            Ahi[kk] = ah; Alo[kk] = al;
        }
        float4 vs0 = *(const float4*)(vecs_s + k0);
        float4 vs1 = *(const float4*)(vecs_s + k0 + 4);
        float4 vd0 = *(const float4*)(vecs_d + k0);
        float4 vd1 = *(const float4*)(vecs_d + k0 + 4);
        ps += xv[0] * vs0.x + xv[1] * vs0.y + xv[2] * vs0.z + xv[3] * vs0.w
            + xv[4] * vs1.x + xv[5] * vs1.y + xv[6] * vs1.z + xv[7] * vs1.w;
        pd += xv[0] * vd0.x + xv[1] * vd0.y + xv[2] * vd0.z + xv[3] * vd0.w
            + xv[4] * vd1.x + xv[5] * vd1.y + xv[6] * vd1.z + xv[7] * vd1.w;
    }
    // rowdot: lane (q,rlo) holds k-slices {32kk+8q..+7}; reduce over q
    ps += __shfl_xor(ps, 16); ps += __shfl_xor(ps, 32);
    pd += __shfl_xor(pd, 16); pd += __shfl_xor(pd, 32);
    if (q == 0 && r < N) { a_s[r] = ps; a_d[r] = pd; }

    #pragma unroll
    for (int ct = 0; ct < COLS / 16; ++ct) {
        int n0 = ct * 16;
        f32x4 acc = {0.f, 0.f, 0.f, 0.f};
        #pragma unroll
        for (int kk = 0; kk < 4; ++kk) {
            bf16x8 bh = *(const bf16x8*)(Bh + (n0 + rlo) * 128 + kk * 32 + q * 8);
            bf16x8 bl = *(const bf16x8*)(Bl + (n0 + rlo) * 128 + kk * 32 + q * 8);
            acc = __builtin_amdgcn_mfma_f32_16x16x32_bf16(Ahi[kk], bh, acc, 0, 0, 0);
            if constexpr (!ABF16)
                acc = __builtin_amdgcn_mfma_f32_16x16x32_bf16(Alo[kk], bh, acc, 0, 0, 0);
            acc = __builtin_amdgcn_mfma_f32_16x16x32_bf16(Ahi[kk], bl, acc, 0, 0, 0);
        }
        #pragma unroll
        for (int i2 = 0; i2 < 4; ++i2) {
            long long orow = wrow0 + q * 4 + i2;
            if (orow < N) H[orow * COLS + n0 + rlo] = f2bf(acc[i2]);
        }
    }
}

// ---------------------------------------------------------------------------
// Fused softmax + aggregate, one wave per dst node, zero atomics, exp inline
// (wave-uniform scalar math is free; the kernel is gather-traffic bound).
// C=128: writes relu(agg+b1) as bf16 -> layer-2 input.  C=64: writes fp32 out.
// ---------------------------------------------------------------------------
template <int C>
__launch_bounds__(256)
__global__ void k_agg(const int* __restrict__ rowptr, const int* __restrict__ perm,
                      const float* __restrict__ a_s, const float* __restrict__ a_d,
                      const unsigned short* __restrict__ H, const float* __restrict__ bias,
                      float* __restrict__ out_f, unsigned short* __restrict__ out_bf, int N) {
    int wave = (int)(((long long)blockIdx.x * 256 + threadIdx.x) >> 6);
    int lane = threadIdx.x & 63;
    if (wave >= N) return;
    int beg = rowptr[wave], end = rowptr[wave + 1];
    float ad = a_d[wave];
    float wsum = 0.f;

    if constexpr (C == 128) {
        const unsigned int* H32 = (const unsigned int*)H;  // 64 uints/row
        float acc0 = 0.f, acc1 = 0.f;
        int i = beg;
        for (; i + 4 <= end; i += 4) {
            int s0 = perm[i], s1 = perm[i + 1], s2 = perm[i + 2], s3 = perm[i + 3];
            float t0 = a_s[s0] + ad, t1 = a_s[s1] + ad;
            float t2 = a_s[s2] + ad, t3 = a_s[s3] + ad;
            t0 = t0 > 0.f ? t0 : NEG_SLOPE * t0;
            t1 = t1 > 0.f ? t1 : NEG_SLOPE * t1;
            t2 = t2 > 0.f ? t2 : NEG_SLOPE * t2;
            t3 = t3 > 0.f ? t3 : NEG_SLOPE * t3;
            float w0 = __expf(t0), w1 = __expf(t1), w2 = __expf(t2), w3 = __expf(t3);
            unsigned int v0 = H32[(long long)s0 * 64 + lane];
            unsigned int v1 = H32[(long long)s1 * 64 + lane];
            unsigned int v2 = H32[(long long)s2 * 64 + lane];
            unsigned int v3 = H32[(long long)s3 * 64 + lane];
            acc0 += w0 * bflo(v0) + w1 * bflo(v1) + w2 * bflo(v2) + w3 * bflo(v3);
            acc1 += w0 * bfhi(v0) + w1 * bfhi(v1) + w2 * bfhi(v2) + w3 * bfhi(v3);
            wsum += w0 + w1 + w2 + w3;
        }
        for (; i < end; ++i) {
            int s = perm[i];
            float t = a_s[s] + ad;
            t = t > 0.f ? t : NEG_SLOPE * t;
            float w = __expf(t);
            unsigned int v = H32[(long long)s * 64 + lane];
            acc0 += w * bflo(v); acc1 += w * bfhi(v);
            wsum += w;
        }
        float inv = (wsum > 0.f) ? __fdividef(1.f, wsum) : 0.f;
        float o0 = fmaxf(acc0 * inv + bias[2 * lane], 0.f);       // + b1, relu
        float o1 = fmaxf(acc1 * inv + bias[2 * lane + 1], 0.f);
        unsigned int pk = (unsigned int)f2bf(o0) | ((unsigned int)f2bf(o1) << 16);
        ((unsigned int*)out_bf)[(long long)wave * 64 + lane] = pk;
    } else {  // C == 64
        float acc = 0.f;
        int i = beg;
        for (; i + 4 <= end; i += 4) {
            int s0 = perm[i], s1 = perm[i + 1], s2 = perm[i + 2], s3 = perm[i + 3];
            float t0 = a_s[s0] + ad, t1 = a_s[s1] + ad;
            float t2 = a_s[s2] + ad, t3 = a_s[s3] + ad;
            t0 = t0 > 0.f ? t0 : NEG_SLOPE * t0;
            t1 = t1 > 0.f ? t1 : NEG_SLOPE * t1;
            t2 = t2 > 0.f ? t2 : NEG_SLOPE * t2;
            t3 = t3 > 0.f ? t3 : NEG_SLOPE * t3;
            float w0 = __expf(t0), w1 = __expf(t1), w2 = __expf(t2), w3 = __expf(t3);
            unsigned int v0 = H[(long long)s0 * 64 + lane];
            unsigned int v1 = H[(long long)s1 * 64 + lane];
            unsigned int v2 = H[(long long)s2 * 64 + lane];
            unsigned int v3 = H[(long long)s3 * 64 + lane];
            acc += w0 * bflo(v0) + w1 * bflo(v1) + w2 * bflo(v2) + w3 * bflo(v3);
            wsum += w0 + w1 + w2 + w3;
        }
        for (; i < end; ++i) {
            int s = perm[i];
            float t = a_s[s] + ad;
            t = t > 0.f ? t : NEG_SLOPE * t;
            float w = __expf(t);
            acc += w * bflo((unsigned int)H[(long long)s * 64 + lane]);
            wsum += w;
        }
        float inv = (wsum > 0.f) ? __fdividef(1.f, wsum) : 0.f;
        out_f[(long long)wave * 64 + lane] = acc * inv + bias[lane];
    }
}

extern "C" void kernel_launch(void* const* d_in, const int* in_sizes, int n_in,
                              void* d_out, int out_size, void* d_ws, size_t ws_size,
                              hipStream_t stream) {
    const float* x   = (const float*)d_in[0];
    const int*   ei  = (const int*)d_in[1];
    const float* Ws1 = (const float*)d_in[2];
    const float* Wd1 = (const float*)d_in[3];
    const float* as1 = (const float*)d_in[4];
    const float* ad1 = (const float*)d_in[5];
    const float* b1  = (const float*)d_in[6];
    const float* Ws2 = (const float*)d_in[7];
    const float* Wd2 = (const float*)d_in[8];
    const float* as2 = (const float*)d_in[9];
    const float* ad2 = (const float*)d_in[10];
    const float* b2  = (const float*)d_in[11];
    float* out = (float*)d_out;

    const int N = in_sizes[0] / F_IN;   // 100000
    const int E = in_sizes[1] / 2;      // 1600000
    const int* srcs = ei;
    const int* dsts = ei + E;

    // Workspace (~60 MB). rank aliases x2bf (dead before k_agg<128> writes it).
    unsigned short* hbuf = (unsigned short*)d_ws;              // N*128 bf16
    unsigned short* x2bf = hbuf + (size_t)N * 128;             // N*128 bf16
    int*   perm   = (int*)(x2bf + (size_t)N * 128);            // E (src only)
    float* a_s1   = (float*)(perm + E);
    float* a_d1   = a_s1 + N;
    float* a_s2   = a_d1 + N;
    float* a_d2   = a_s2 + N;
    int*   cnt    = (int*)(a_d2 + N);                          // N
    int*   rowptr = cnt + N;                                   // N+1 (pad to +4)
    int*   bsum   = rowptr + N + 4;                            // 64 (16B-align tail)
    int*   bpre   = bsum + 64;                                 // 64
    unsigned short* w1hi = (unsigned short*)(bpre + 64);       // 16384
    unsigned short* w1lo = w1hi + 16384;
    unsigned short* w2hi = w1lo + 16384;                       // 8192
    unsigned short* w2lo = w2hi + 8192;
    float* vecs   = (float*)(w2lo + 8192);                     // 512
    int*   rank   = (int*)x2bf;                                // E (alias)

    const int nb = (N + SCAN_CHUNK - 1) / SCAN_CHUNK;

    // ---- prep (cnt zero + attention vecs + W hi/lo transpose) ----
    k_prep<<<(N + 255) / 256, 256, 0, stream>>>(Ws1, Wd1, as1, ad1, Ws2, Wd2,
                                                as2, ad2, vecs, cnt,
                                                w1hi, w1lo, w2hi, w2lo, N);
    // ---- CSR build (once, reused by both layers) ----
    k_hist<<<(E + 255) / 256, 256, 0, stream>>>(dsts, cnt, rank, E);
    k_blocksum<<<nb, 256, 0, stream>>>(cnt, bsum, N);
    k_scan_bsum<<<1, 64, 0, stream>>>(bsum, bpre, nb, rowptr, N);
    k_scan_chunks<<<nb, 256, 0, stream>>>(cnt, bpre, rowptr, N);
    k_place<<<(E + 255) / 256, 256, 0, stream>>>(srcs, dsts, rowptr, rank, perm, E);

    // ---- Layer 1: fp32 X, split-bf16 MFMA ----
    k_gemm_mfma<128, false><<<(N + 63) / 64, 256, 0, stream>>>(
        x, w1hi, w1lo, vecs, vecs + 128, hbuf, a_s1, a_d1, N);
    k_agg<128><<<(N + 3) / 4, 256, 0, stream>>>(
        rowptr, perm, a_s1, a_d1, hbuf, b1, nullptr, x2bf, N);

    // ---- Layer 2: bf16 X (relu'd, b1 folded in by agg) ----
    k_gemm_mfma<64, true><<<(N + 63) / 64, 256, 0, stream>>>(
        x2bf, w2hi, w2lo, vecs + 256, vecs + 384, hbuf, a_s2, a_d2, N);
    k_agg<64><<<(N + 3) / 4, 256, 0, stream>>>(
        rowptr, perm, a_s2, a_d2, hbuf, b2, out, nullptr, N);
}

// Round 6
// 437.477 us; speedup vs baseline: 10.4023x; 1.0426x over previous
//
#include <hip/hip_runtime.h>

#define F_IN 128
#define NEG_SLOPE 0.2f
#define SCAN_CHUNK 2048  // 256 threads x 8 elements

typedef __attribute__((ext_vector_type(8))) short bf16x8;
typedef __attribute__((ext_vector_type(4))) float f32x4;

__device__ inline unsigned short f2bf(float f) {  // fp32 -> bf16 RNE
    unsigned int u = __float_as_uint(f);
    unsigned int r = (u + 0x7fffu + ((u >> 16) & 1u)) >> 16;
    return (unsigned short)r;
}
__device__ inline float bf2f(unsigned short h) { return __uint_as_float((unsigned int)h << 16); }
__device__ inline float bflo(unsigned int u) { return __uint_as_float(u << 16); }
__device__ inline float bfhi(unsigned int u) { return __uint_as_float(u & 0xffff0000u); }

// ---------------------------------------------------------------------------
// Prep: zero CSR counters; block 0 computes the 4 projected attention vectors
// v = W@att; blocks 1..96 transpose W1/W2 into bf16 hi/lo Wt[n][k].
// ---------------------------------------------------------------------------
__global__ void k_prep(const float* __restrict__ Ws1, const float* __restrict__ Wd1,
                       const float* __restrict__ as1, const float* __restrict__ ad1,
                       const float* __restrict__ Ws2, const float* __restrict__ Wd2,
                       const float* __restrict__ as2, const float* __restrict__ ad2,
                       float* __restrict__ vecs, int* __restrict__ cnt,
                       unsigned short* __restrict__ w1hi, unsigned short* __restrict__ w1lo,
                       unsigned short* __restrict__ w2hi, unsigned short* __restrict__ w2lo,
                       int N) {
    int bid = blockIdx.x, tid = threadIdx.x;
    int i = bid * 256 + tid;
    if (i < N) cnt[i] = 0;
    if (bid == 0 && tid < 128) {
        int f = tid;
        float s1 = 0.f, d1 = 0.f, s2 = 0.f, d2 = 0.f;
        for (int c = 0; c < 128; ++c) {
            s1 += Ws1[f * 128 + c] * as1[c];
            d1 += Wd1[f * 128 + c] * ad1[c];
        }
        for (int c = 0; c < 64; ++c) {
            s2 += Ws2[f * 64 + c] * as2[c];
            d2 += Wd2[f * 64 + c] * ad2[c];
        }
        vecs[f] = s1; vecs[128 + f] = d1; vecs[256 + f] = s2; vecs[384 + f] = d2;
    } else if (bid >= 1 && bid < 65) {          // W1: 128n x 128k
        int idx = (bid - 1) * 256 + tid;        // < 16384
        int n = idx >> 7, k = idx & 127;
        float w = Ws1[k * 128 + n];
        unsigned short h = f2bf(w);
        w1hi[idx] = h;
        w1lo[idx] = f2bf(w - bf2f(h));
    } else if (bid >= 65 && bid < 97) {         // W2: 64n x 128k
        int idx = (bid - 65) * 256 + tid;       // < 8192
        int n = idx >> 7, k = idx & 127;
        float w = Ws2[k * 64 + n];
        unsigned short h = f2bf(w);
        w2hi[idx] = h;
        w2lo[idx] = f2bf(w - bf2f(h));
    }
}

// ---------------------------------------------------------------------------
// CSR build: hist (rank = old count) -> 3-phase scan -> place (src only)
// ---------------------------------------------------------------------------
__global__ void k_hist(const int* __restrict__ dsts, int* __restrict__ cnt,
                       int* __restrict__ rank, int E) {
    int e = blockIdx.x * 256 + threadIdx.x;
    if (e < E) rank[e] = atomicAdd(&cnt[dsts[e]], 1);
}

__global__ void k_blocksum(const int* __restrict__ cnt, int* __restrict__ bsum, int N) {
    __shared__ int sh[256];
    int t = threadIdx.x;
    long long base = (long long)blockIdx.x * SCAN_CHUNK + (long long)t * 8;
    int s = 0;
    #pragma unroll
    for (int k = 0; k < 8; ++k) {
        long long i = base + k;
        if (i < N) s += cnt[i];
    }
    sh[t] = s;
    __syncthreads();
    for (int off = 128; off; off >>= 1) {
        if (t < off) sh[t] += sh[t + off];
        __syncthreads();
    }
    if (t == 0) bsum[blockIdx.x] = sh[0];
}

__global__ void k_scan_bsum(const int* __restrict__ bsum, int* __restrict__ bpre,
                            int nb, int* __restrict__ rowptr, int N) {
    if (threadIdx.x == 0 && blockIdx.x == 0) {
        int off = 0;
        for (int b = 0; b < nb; ++b) { bpre[b] = off; off += bsum[b]; }
        rowptr[N] = off;  // == E
    }
}

__global__ void k_scan_chunks(const int* __restrict__ cnt, const int* __restrict__ bpre,
                              int* __restrict__ rowptr, int N) {
    __shared__ int sh[256];
    int t = threadIdx.x;
    long long base = (long long)blockIdx.x * SCAN_CHUNK + (long long)t * 8;
    int loc[8];
    int s = 0;
    #pragma unroll
    for (int k = 0; k < 8; ++k) {
        long long i = base + k;
        int v = (i < N) ? cnt[i] : 0;
        loc[k] = s;
        s += v;
    }
    sh[t] = s;
    __syncthreads();
    for (int off = 1; off < 256; off <<= 1) {
        int tmp = (t >= off) ? sh[t - off] : 0;
        __syncthreads();
        sh[t] += tmp;
        __syncthreads();
    }
    int toff = bpre[blockIdx.x] + sh[t] - s;
    #pragma unroll
    for (int k = 0; k < 8; ++k) {
        long long i = base + k;
        if (i < N) rowptr[i] = toff + loc[k];
    }
}

__global__ void k_place(const int* __restrict__ srcs, const int* __restrict__ dsts,
                        const int* __restrict__ rowptr, const int* __restrict__ rank,
                        int* __restrict__ perm_src, int E) {
    int e = blockIdx.x * 256 + threadIdx.x;
    if (e >= E) return;
    perm_src[rowptr[dsts[e]] + rank[e]] = srcs[e];
}

// ---------------------------------------------------------------------------
// MFMA GEMM: H(bf16)[N][COLS] = X[N][128] @ W[128][COLS], fused rowdots.
// mfma_f32_16x16x32_bf16: A[m=lane&15][k=quad*8+j], B[k][n=lane&15],
// D[row=quad*4+reg][col=lane&15].  Layer1: fp32 X split bf16 hi/lo (3 MFMA);
// Layer2: bf16 X (2 MFMA).  Block = 4 waves x 16 rows = 64 rows.
// ---------------------------------------------------------------------------
template <int COLS, bool ABF16>
__launch_bounds__(256)
__global__ void k_gemm_mfma(const void* __restrict__ Xv,
                            const unsigned short* __restrict__ Bh,
                            const unsigned short* __restrict__ Bl,
                            const float* __restrict__ vecs_s,
                            const float* __restrict__ vecs_d,
                            unsigned short* __restrict__ H,
                            float* __restrict__ a_s, float* __restrict__ a_d, int N) {
    int tid = threadIdx.x;
    int wave = tid >> 6, lane = tid & 63;
    int q = lane >> 4, rlo = lane & 15;
    long long wrow0 = (long long)blockIdx.x * 64 + wave * 16;
    long long r = wrow0 + rlo;
    long long rr = (r < N) ? r : (long long)(N - 1);  // clamp loads; guard stores

    bf16x8 Ahi[4], Alo[4];
    float ps = 0.f, pd = 0.f;
    #pragma unroll
    for (int kk = 0; kk < 4; ++kk) {
        int k0 = kk * 32 + q * 8;
        float xv[8];
        if constexpr (ABF16) {
            const unsigned short* Xu = (const unsigned short*)Xv;
            bf16x8 av = *(const bf16x8*)(Xu + rr * 128 + k0);
            Ahi[kk] = av;
            #pragma unroll
            for (int j = 0; j < 8; ++j) xv[j] = bf2f((unsigned short)av[j]);
        } else {
            const float* Xf = (const float*)Xv;
            float4 x0 = *(const float4*)(Xf + rr * 128 + k0);
            float4 x1 = *(const float4*)(Xf + rr * 128 + k0 + 4);
            xv[0] = x0.x; xv[1] = x0.y; xv[2] = x0.z; xv[3] = x0.w;
            xv[4] = x1.x; xv[5] = x1.y; xv[6] = x1.z; xv[7] = x1.w;
            bf16x8 ah, al;
            #pragma unroll
            for (int j = 0; j < 8; ++j) {
                unsigned short h = f2bf(xv[j]);
                ah[j] = (short)h;
                al[j] = (short)f2bf(xv[j] - bf2f(h));
            }
            Ahi[kk] = ah; Alo[kk] = al;
        }
        float4 vs0 = *(const float4*)(vecs_s + k0);
        float4 vs1 = *(const float4*)(vecs_s + k0 + 4);
        float4 vd0 = *(const float4*)(vecs_d + k0);
        float4 vd1 = *(const float4*)(vecs_d + k0 + 4);
        ps += xv[0] * vs0.x + xv[1] * vs0.y + xv[2] * vs0.z + xv[3] * vs0.w
            + xv[4] * vs1.x + xv[5] * vs1.y + xv[6] * vs1.z + xv[7] * vs1.w;
        pd += xv[0] * vd0.x + xv[1] * vd0.y + xv[2] * vd0.z + xv[3] * vd0.w
            + xv[4] * vd1.x + xv[5] * vd1.y + xv[6] * vd1.z + xv[7] * vd1.w;
    }
    ps += __shfl_xor(ps, 16); ps += __shfl_xor(ps, 32);
    pd += __shfl_xor(pd, 16); pd += __shfl_xor(pd, 32);
    if (q == 0 && r < N) { a_s[r] = ps; a_d[r] = pd; }

    #pragma unroll
    for (int ct = 0; ct < COLS / 16; ++ct) {
        int n0 = ct * 16;
        f32x4 acc = {0.f, 0.f, 0.f, 0.f};
        #pragma unroll
        for (int kk = 0; kk < 4; ++kk) {
            bf16x8 bh = *(const bf16x8*)(Bh + (n0 + rlo) * 128 + kk * 32 + q * 8);
            bf16x8 bl = *(const bf16x8*)(Bl + (n0 + rlo) * 128 + kk * 32 + q * 8);
            acc = __builtin_amdgcn_mfma_f32_16x16x32_bf16(Ahi[kk], bh, acc, 0, 0, 0);
            if constexpr (!ABF16)
                acc = __builtin_amdgcn_mfma_f32_16x16x32_bf16(Alo[kk], bh, acc, 0, 0, 0);
            acc = __builtin_amdgcn_mfma_f32_16x16x32_bf16(Ahi[kk], bl, acc, 0, 0, 0);
        }
        #pragma unroll
        for (int i2 = 0; i2 < 4; ++i2) {
            long long orow = wrow0 + q * 4 + i2;
            if (orow < N) H[orow * COLS + n0 + rlo] = f2bf(acc[i2]);
        }
    }
}

// ---------------------------------------------------------------------------
// Layer-1 aggregate (C=128): one wave per dst row; 8-deep unroll; src indices
// forced to SGPRs (readfirstlane) so perm/a_s broadcasts ride the scalar path
// and VMEM issues only the 8 independent 256 B H-row gathers per group.
// Writes relu(agg + b1) as packed bf16 -> layer-2 input.
// ---------------------------------------------------------------------------
__launch_bounds__(256)
__global__ void k_agg128(const int* __restrict__ rowptr, const int* __restrict__ perm,
                         const float* __restrict__ a_s, const float* __restrict__ a_d,
                         const unsigned short* __restrict__ H, const float* __restrict__ bias,
                         unsigned short* __restrict__ out_bf, int N) {
    int wave = (int)(((long long)blockIdx.x * 256 + threadIdx.x) >> 6);
    int lane = threadIdx.x & 63;
    if (wave >= N) return;
    int beg = __builtin_amdgcn_readfirstlane(rowptr[wave]);
    int end = __builtin_amdgcn_readfirstlane(rowptr[wave + 1]);
    float ad = __uint_as_float(__builtin_amdgcn_readfirstlane(__float_as_uint(a_d[wave])));

    const unsigned int* H32 = (const unsigned int*)H;  // 64 uints/row
    float acc0 = 0.f, acc1 = 0.f, wsum = 0.f;
    int i = beg;
    for (; i + 8 <= end; i += 8) {
        int s[8];
        unsigned int v[8];
        #pragma unroll
        for (int j = 0; j < 8; ++j)
            s[j] = __builtin_amdgcn_readfirstlane(perm[i + j]);
        #pragma unroll
        for (int j = 0; j < 8; ++j)
            v[j] = H32[(long long)s[j] * 64 + lane];
        #pragma unroll
        for (int j = 0; j < 8; ++j) {
            float t = a_s[s[j]] + ad;
            t = t > 0.f ? t : NEG_SLOPE * t;
            float w = __expf(t);
            acc0 += w * bflo(v[j]);
            acc1 += w * bfhi(v[j]);
            wsum += w;
        }
    }
    for (; i < end; ++i) {
        int s = __builtin_amdgcn_readfirstlane(perm[i]);
        unsigned int v = H32[(long long)s * 64 + lane];
        float t = a_s[s] + ad;
        t = t > 0.f ? t : NEG_SLOPE * t;
        float w = __expf(t);
        acc0 += w * bflo(v); acc1 += w * bfhi(v);
        wsum += w;
    }
    float inv = (wsum > 0.f) ? __fdividef(1.f, wsum) : 0.f;  // deg-0 -> bias only
    float o0 = fmaxf(acc0 * inv + bias[2 * lane], 0.f);      // + b1, relu
    float o1 = fmaxf(acc1 * inv + bias[2 * lane + 1], 0.f);
    unsigned int pk = (unsigned int)f2bf(o0) | ((unsigned int)f2bf(o1) << 16);
    ((unsigned int*)out_bf)[(long long)wave * 64 + lane] = pk;
}

// ---------------------------------------------------------------------------
// Layer-2 aggregate (C=64): half-wave per edge (2 edges per wave step, each
// lane a full 4 B uint of the 128 B row -> 256 B per wave load-instruction),
// 4-deep unroll = 8 rows in flight.  Cross-half shfl merge at the end.
// ---------------------------------------------------------------------------
__launch_bounds__(256)
__global__ void k_agg64(const int* __restrict__ rowptr, const int* __restrict__ perm,
                        const float* __restrict__ a_s, const float* __restrict__ a_d,
                        const unsigned short* __restrict__ H, const float* __restrict__ bias,
                        float* __restrict__ out, int N) {
    int wave = (int)(((long long)blockIdx.x * 256 + threadIdx.x) >> 6);
    int lane = threadIdx.x & 63;
    if (wave >= N) return;
    int c = lane & 31, h = lane >> 5;  // half-wave id
    int beg = __builtin_amdgcn_readfirstlane(rowptr[wave]);
    int end = __builtin_amdgcn_readfirstlane(rowptr[wave + 1]);
    float ad = __uint_as_float(__builtin_amdgcn_readfirstlane(__float_as_uint(a_d[wave])));

    const unsigned int* H32 = (const unsigned int*)H;  // 32 uints/row
    float acc0 = 0.f, acc1 = 0.f, wsum = 0.f;
    int base = beg;
    for (; base + 8 <= end; base += 8) {
        int s[4];
        unsigned int v[4];
        #pragma unroll
        for (int j = 0; j < 4; ++j)
            s[j] = perm[base + h + 2 * j];
        #pragma unroll
        for (int j = 0; j < 4; ++j)
            v[j] = H32[(long long)s[j] * 32 + c];
        #pragma unroll
        for (int j = 0; j < 4; ++j) {
            float t = a_s[s[j]] + ad;
            t = t > 0.f ? t : NEG_SLOPE * t;
            float w = __expf(t);
            acc0 += w * bflo(v[j]);
            acc1 += w * bfhi(v[j]);
            wsum += w;
        }
    }
    for (int i = base + h; i < end; i += 2) {
        int s = perm[i];
        unsigned int v = H32[(long long)s * 32 + c];
        float t = a_s[s] + ad;
        t = t > 0.f ? t : NEG_SLOPE * t;
        float w = __expf(t);
        acc0 += w * bflo(v); acc1 += w * bfhi(v);
        wsum += w;
    }
    // merge the two half-waves (independent edge subsets, same dst)
    acc0 += __shfl_xor(acc0, 32);
    acc1 += __shfl_xor(acc1, 32);
    wsum += __shfl_xor(wsum, 32);
    if (h == 0) {
        float inv = (wsum > 0.f) ? __fdividef(1.f, wsum) : 0.f;
        float2 o;
        o.x = acc0 * inv + bias[2 * c];
        o.y = acc1 * inv + bias[2 * c + 1];
        *(float2*)(out + (long long)wave * 64 + 2 * c) = o;
    }
}

extern "C" void kernel_launch(void* const* d_in, const int* in_sizes, int n_in,
                              void* d_out, int out_size, void* d_ws, size_t ws_size,
                              hipStream_t stream) {
    const float* x   = (const float*)d_in[0];
    const int*   ei  = (const int*)d_in[1];
    const float* Ws1 = (const float*)d_in[2];
    const float* Wd1 = (const float*)d_in[3];
    const float* as1 = (const float*)d_in[4];
    const float* ad1 = (const float*)d_in[5];
    const float* b1  = (const float*)d_in[6];
    const float* Ws2 = (const float*)d_in[7];
    const float* Wd2 = (const float*)d_in[8];
    const float* as2 = (const float*)d_in[9];
    const float* ad2 = (const float*)d_in[10];
    const float* b2  = (const float*)d_in[11];
    float* out = (float*)d_out;

    const int N = in_sizes[0] / F_IN;   // 100000
    const int E = in_sizes[1] / 2;      // 1600000
    const int* srcs = ei;
    const int* dsts = ei + E;

    // Workspace (~60 MB). rank aliases x2bf (dead before k_agg128 writes it).
    unsigned short* hbuf = (unsigned short*)d_ws;              // N*128 bf16
    unsigned short* x2bf = hbuf + (size_t)N * 128;             // N*128 bf16
    int*   perm   = (int*)(x2bf + (size_t)N * 128);            // E (src only)
    float* a_s1   = (float*)(perm + E);
    float* a_d1   = a_s1 + N;
    float* a_s2   = a_d1 + N;
    float* a_d2   = a_s2 + N;
    int*   cnt    = (int*)(a_d2 + N);                          // N
    int*   rowptr = cnt + N;                                   // N+1 (pad to +4)
    int*   bsum   = rowptr + N + 4;                            // 64
    int*   bpre   = bsum + 64;                                 // 64
    unsigned short* w1hi = (unsigned short*)(bpre + 64);       // 16384
    unsigned short* w1lo = w1hi + 16384;
    unsigned short* w2hi = w1lo + 16384;                       // 8192
    unsigned short* w2lo = w2hi + 8192;
    float* vecs   = (float*)(w2lo + 8192);                     // 512
    int*   rank   = (int*)x2bf;                                // E (alias)

    const int nb = (N + SCAN_CHUNK - 1) / SCAN_CHUNK;

    // ---- prep (cnt zero + attention vecs + W hi/lo transpose) ----
    k_prep<<<(N + 255) / 256, 256, 0, stream>>>(Ws1, Wd1, as1, ad1, Ws2, Wd2,
                                                as2, ad2, vecs, cnt,
                                                w1hi, w1lo, w2hi, w2lo, N);
    // ---- CSR build (once, reused by both layers) ----
    k_hist<<<(E + 255) / 256, 256, 0, stream>>>(dsts, cnt, rank, E);
    k_blocksum<<<nb, 256, 0, stream>>>(cnt, bsum, N);
    k_scan_bsum<<<1, 64, 0, stream>>>(bsum, bpre, nb, rowptr, N);
    k_scan_chunks<<<nb, 256, 0, stream>>>(cnt, bpre, rowptr, N);
    k_place<<<(E + 255) / 256, 256, 0, stream>>>(srcs, dsts, rowptr, rank, perm, E);

    // ---- Layer 1: fp32 X, split-bf16 MFMA ----
    k_gemm_mfma<128, false><<<(N + 63) / 64, 256, 0, stream>>>(
        x, w1hi, w1lo, vecs, vecs + 128, hbuf, a_s1, a_d1, N);
    k_agg128<<<(N + 3) / 4, 256, 0, stream>>>(
        rowptr, perm, a_s1, a_d1, hbuf, b1, x2bf, N);

    // ---- Layer 2: bf16 X (relu'd, b1 folded in by agg) ----
    k_gemm_mfma<64, true><<<(N + 63) / 64, 256, 0, stream>>>(
        x2bf, w2hi, w2lo, vecs + 256, vecs + 384, hbuf, a_s2, a_d2, N);
    k_agg64<<<(N + 3) / 4, 256, 0, stream>>>(
        rowptr, perm, a_s2, a_d2, hbuf, b2, out, N);
}

// Round 7
// 383.594 us; speedup vs baseline: 11.8636x; 1.1405x over previous
//
#include <hip/hip_runtime.h>

#define F_IN 128
#define NEG_SLOPE 0.2f
#define SCAN_CHUNK 2048  // 256 threads x 8 elements

typedef __attribute__((ext_vector_type(8))) short bf16x8;
typedef __attribute__((ext_vector_type(4))) float f32x4;

__device__ inline unsigned short f2bf(float f) {  // fp32 -> bf16 RNE
    unsigned int u = __float_as_uint(f);
    unsigned int r = (u + 0x7fffu + ((u >> 16) & 1u)) >> 16;
    return (unsigned short)r;
}
__device__ inline float bf2f(unsigned short h) { return __uint_as_float((unsigned int)h << 16); }
__device__ inline float bflo(unsigned int u) { return __uint_as_float(u << 16); }
__device__ inline float bfhi(unsigned int u) { return __uint_as_float(u & 0xffff0000u); }

// Swizzled ("fragment-order") B index for mfma_f32_16x16x32_bf16 consumption:
// element (n,k) -> ((ct*4+kk)*64 + q*16 + rlo)*8 + j  with ct=n>>4, rlo=n&15,
// kk=k>>5, q=(k>>3)&3, j=k&7.  A wave's load of fragment (ct,kk) is then
// Bsw[(ct*4+kk)*64 + lane]: lane-contiguous 1 KB -> one coalesced transaction.
__device__ inline int bswiz(int n, int k) {
    int ct = n >> 4, rlo = n & 15, kk = k >> 5, q = (k >> 3) & 3, j = k & 7;
    return (((ct * 4 + kk) * 64 + q * 16 + rlo) << 3) + j;
}

// ---------------------------------------------------------------------------
// Prep: zero CSR counters; block 0 computes the 4 projected attention vectors
// v = W@att; blocks 1..96 build swizzled bf16 hi/lo copies of W1/W2.
// ---------------------------------------------------------------------------
__global__ void k_prep(const float* __restrict__ Ws1, const float* __restrict__ Wd1,
                       const float* __restrict__ as1, const float* __restrict__ ad1,
                       const float* __restrict__ Ws2, const float* __restrict__ Wd2,
                       const float* __restrict__ as2, const float* __restrict__ ad2,
                       float* __restrict__ vecs, int* __restrict__ cnt,
                       unsigned short* __restrict__ w1hi, unsigned short* __restrict__ w1lo,
                       unsigned short* __restrict__ w2hi, unsigned short* __restrict__ w2lo,
                       int N) {
    int bid = blockIdx.x, tid = threadIdx.x;
    int i = bid * 256 + tid;
    if (i < N) cnt[i] = 0;
    if (bid == 0 && tid < 128) {
        int f = tid;
        float s1 = 0.f, d1 = 0.f, s2 = 0.f, d2 = 0.f;
        for (int c = 0; c < 128; ++c) {
            s1 += Ws1[f * 128 + c] * as1[c];
            d1 += Wd1[f * 128 + c] * ad1[c];
        }
        for (int c = 0; c < 64; ++c) {
            s2 += Ws2[f * 64 + c] * as2[c];
            d2 += Wd2[f * 64 + c] * ad2[c];
        }
        vecs[f] = s1; vecs[128 + f] = d1; vecs[256 + f] = s2; vecs[384 + f] = d2;
    } else if (bid >= 1 && bid < 65) {          // W1: n<128, k<128
        int idx = (bid - 1) * 256 + tid;        // < 16384
        int n = idx >> 7, k = idx & 127;
        float w = Ws1[k * 128 + n];
        unsigned short h = f2bf(w);
        int si = bswiz(n, k);
        w1hi[si] = h;
        w1lo[si] = f2bf(w - bf2f(h));
    } else if (bid >= 65 && bid < 97) {         // W2: n<64, k<128
        int idx = (bid - 65) * 256 + tid;       // < 8192
        int n = idx >> 7, k = idx & 127;
        float w = Ws2[k * 64 + n];
        unsigned short h = f2bf(w);
        int si = bswiz(n, k);
        w2hi[si] = h;
        w2lo[si] = f2bf(w - bf2f(h));
    }
}

// ---------------------------------------------------------------------------
// CSR build: hist (rank = old count) -> 3-phase scan -> place (src only)
// ---------------------------------------------------------------------------
__global__ void k_hist(const int* __restrict__ dsts, int* __restrict__ cnt,
                       int* __restrict__ rank, int E) {
    int e = blockIdx.x * 256 + threadIdx.x;
    if (e < E) rank[e] = atomicAdd(&cnt[dsts[e]], 1);
}

__global__ void k_blocksum(const int* __restrict__ cnt, int* __restrict__ bsum, int N) {
    __shared__ int sh[256];
    int t = threadIdx.x;
    long long base = (long long)blockIdx.x * SCAN_CHUNK + (long long)t * 8;
    int s = 0;
    #pragma unroll
    for (int k = 0; k < 8; ++k) {
        long long i = base + k;
        if (i < N) s += cnt[i];
    }
    sh[t] = s;
    __syncthreads();
    for (int off = 128; off; off >>= 1) {
        if (t < off) sh[t] += sh[t + off];
        __syncthreads();
    }
    if (t == 0) bsum[blockIdx.x] = sh[0];
}

__global__ void k_scan_bsum(const int* __restrict__ bsum, int* __restrict__ bpre,
                            int nb, int* __restrict__ rowptr, int N) {
    if (threadIdx.x == 0 && blockIdx.x == 0) {
        int off = 0;
        for (int b = 0; b < nb; ++b) { bpre[b] = off; off += bsum[b]; }
        rowptr[N] = off;  // == E
    }
}

__global__ void k_scan_chunks(const int* __restrict__ cnt, const int* __restrict__ bpre,
                              int* __restrict__ rowptr, int N) {
    __shared__ int sh[256];
    int t = threadIdx.x;
    long long base = (long long)blockIdx.x * SCAN_CHUNK + (long long)t * 8;
    int loc[8];
    int s = 0;
    #pragma unroll
    for (int k = 0; k < 8; ++k) {
        long long i = base + k;
        int v = (i < N) ? cnt[i] : 0;
        loc[k] = s;
        s += v;
    }
    sh[t] = s;
    __syncthreads();
    for (int off = 1; off < 256; off <<= 1) {
        int tmp = (t >= off) ? sh[t - off] : 0;
        __syncthreads();
        sh[t] += tmp;
        __syncthreads();
    }
    int toff = bpre[blockIdx.x] + sh[t] - s;
    #pragma unroll
    for (int k = 0; k < 8; ++k) {
        long long i = base + k;
        if (i < N) rowptr[i] = toff + loc[k];
    }
}

__global__ void k_place(const int* __restrict__ srcs, const int* __restrict__ dsts,
                        const int* __restrict__ rowptr, const int* __restrict__ rank,
                        int* __restrict__ perm_src, int E) {
    int e = blockIdx.x * 256 + threadIdx.x;
    if (e >= E) return;
    perm_src[rowptr[dsts[e]] + rank[e]] = srcs[e];
}

// ---------------------------------------------------------------------------
// MFMA GEMM v2: H(bf16)[N][COLS] = X[N][128] @ W[128][COLS], fused rowdots.
// Swizzled B (coalesced 1 KB fragment loads) + RT=2 row-tiles per wave
// (B-fragments amortized over 32 rows).  Layer1 (!ABF16): fp32 X split
// bf16 hi/lo, 3 MFMAs/frag; Layer2 (ABF16): bf16 X, 2 MFMAs/frag.
// Block = 4 waves x 32 rows = 128 rows.
// ---------------------------------------------------------------------------
template <int COLS, bool ABF16>
__launch_bounds__(256)
__global__ void k_gemm_mfma(const void* __restrict__ Xv,
                            const unsigned short* __restrict__ Bh,
                            const unsigned short* __restrict__ Bl,
                            const float* __restrict__ vecs_s,
                            const float* __restrict__ vecs_d,
                            unsigned short* __restrict__ H,
                            float* __restrict__ a_s, float* __restrict__ a_d, int N) {
    int tid = threadIdx.x;
    int wave = tid >> 6, lane = tid & 63;
    int q = lane >> 4, rlo = lane & 15;
    long long wrow0 = (long long)blockIdx.x * 128 + wave * 32;

    bf16x8 Ahi[2][4], Alo[2][4];
    #pragma unroll
    for (int rt = 0; rt < 2; ++rt) {
        long long r = wrow0 + rt * 16 + rlo;
        long long rr = (r < N) ? r : (long long)(N - 1);  // clamp loads
        float ps = 0.f, pd = 0.f;
        #pragma unroll
        for (int kk = 0; kk < 4; ++kk) {
            int k0 = kk * 32 + q * 8;
            float xv[8];
            if constexpr (ABF16) {
                const unsigned short* Xu = (const unsigned short*)Xv;
                bf16x8 av = *(const bf16x8*)(Xu + rr * 128 + k0);
                Ahi[rt][kk] = av;
                #pragma unroll
                for (int j = 0; j < 8; ++j) xv[j] = bf2f((unsigned short)av[j]);
            } else {
                const float* Xf = (const float*)Xv;
                float4 x0 = *(const float4*)(Xf + rr * 128 + k0);
                float4 x1 = *(const float4*)(Xf + rr * 128 + k0 + 4);
                xv[0] = x0.x; xv[1] = x0.y; xv[2] = x0.z; xv[3] = x0.w;
                xv[4] = x1.x; xv[5] = x1.y; xv[6] = x1.z; xv[7] = x1.w;
                bf16x8 ah, al;
                #pragma unroll
                for (int j = 0; j < 8; ++j) {
                    unsigned short h = f2bf(xv[j]);
                    ah[j] = (short)h;
                    al[j] = (short)f2bf(xv[j] - bf2f(h));
                }
                Ahi[rt][kk] = ah; Alo[rt][kk] = al;
            }
            float4 vs0 = *(const float4*)(vecs_s + k0);
            float4 vs1 = *(const float4*)(vecs_s + k0 + 4);
            float4 vd0 = *(const float4*)(vecs_d + k0);
            float4 vd1 = *(const float4*)(vecs_d + k0 + 4);
            ps += xv[0] * vs0.x + xv[1] * vs0.y + xv[2] * vs0.z + xv[3] * vs0.w
                + xv[4] * vs1.x + xv[5] * vs1.y + xv[6] * vs1.z + xv[7] * vs1.w;
            pd += xv[0] * vd0.x + xv[1] * vd0.y + xv[2] * vd0.z + xv[3] * vd0.w
                + xv[4] * vd1.x + xv[5] * vd1.y + xv[6] * vd1.z + xv[7] * vd1.w;
        }
        ps += __shfl_xor(ps, 16); ps += __shfl_xor(ps, 32);
        pd += __shfl_xor(pd, 16); pd += __shfl_xor(pd, 32);
        if (q == 0 && r < N) { a_s[r] = ps; a_d[r] = pd; }
    }

    const bf16x8* Bh8 = (const bf16x8*)Bh;
    const bf16x8* Bl8 = (const bf16x8*)Bl;
    #pragma unroll 1   // keep rolled: bounds VGPRs; 8 loads in flight per iter
    for (int ct = 0; ct < COLS / 16; ++ct) {
        bf16x8 bh[4], bl[4];
        #pragma unroll
        for (int kk = 0; kk < 4; ++kk) {
            bh[kk] = Bh8[(ct * 4 + kk) * 64 + lane];
            bl[kk] = Bl8[(ct * 4 + kk) * 64 + lane];
        }
        f32x4 acc0 = {0.f, 0.f, 0.f, 0.f};
        f32x4 acc1 = {0.f, 0.f, 0.f, 0.f};
        #pragma unroll
        for (int kk = 0; kk < 4; ++kk) {
            acc0 = __builtin_amdgcn_mfma_f32_16x16x32_bf16(Ahi[0][kk], bh[kk], acc0, 0, 0, 0);
            acc1 = __builtin_amdgcn_mfma_f32_16x16x32_bf16(Ahi[1][kk], bh[kk], acc1, 0, 0, 0);
            if constexpr (!ABF16) {
                acc0 = __builtin_amdgcn_mfma_f32_16x16x32_bf16(Alo[0][kk], bh[kk], acc0, 0, 0, 0);
                acc1 = __builtin_amdgcn_mfma_f32_16x16x32_bf16(Alo[1][kk], bh[kk], acc1, 0, 0, 0);
            }
            acc0 = __builtin_amdgcn_mfma_f32_16x16x32_bf16(Ahi[0][kk], bl[kk], acc0, 0, 0, 0);
            acc1 = __builtin_amdgcn_mfma_f32_16x16x32_bf16(Ahi[1][kk], bl[kk], acc1, 0, 0, 0);
        }
        #pragma unroll
        for (int i2 = 0; i2 < 4; ++i2) {
            long long o0 = wrow0 + q * 4 + i2;
            long long o1 = wrow0 + 16 + q * 4 + i2;
            if (o0 < N) H[o0 * COLS + ct * 16 + rlo] = f2bf(acc0[i2]);
            if (o1 < N) H[o1 * COLS + ct * 16 + rlo] = f2bf(acc1[i2]);
        }
    }
}

// ---------------------------------------------------------------------------
// Layer-1 aggregate (C=128): one wave per dst row; 8-deep unroll; scalar-path
// broadcasts (readfirstlane).  Writes relu(agg + b1) as packed bf16.
// ---------------------------------------------------------------------------
__launch_bounds__(256)
__global__ void k_agg128(const int* __restrict__ rowptr, const int* __restrict__ perm,
                         const float* __restrict__ a_s, const float* __restrict__ a_d,
                         const unsigned short* __restrict__ H, const float* __restrict__ bias,
                         unsigned short* __restrict__ out_bf, int N) {
    int wave = (int)(((long long)blockIdx.x * 256 + threadIdx.x) >> 6);
    int lane = threadIdx.x & 63;
    if (wave >= N) return;
    int beg = __builtin_amdgcn_readfirstlane(rowptr[wave]);
    int end = __builtin_amdgcn_readfirstlane(rowptr[wave + 1]);
    float ad = __uint_as_float(__builtin_amdgcn_readfirstlane(__float_as_uint(a_d[wave])));

    const unsigned int* H32 = (const unsigned int*)H;  // 64 uints/row
    float acc0 = 0.f, acc1 = 0.f, wsum = 0.f;
    int i = beg;
    for (; i + 8 <= end; i += 8) {
        int s[8];
        unsigned int v[8];
        #pragma unroll
        for (int j = 0; j < 8; ++j)
            s[j] = __builtin_amdgcn_readfirstlane(perm[i + j]);
        #pragma unroll
        for (int j = 0; j < 8; ++j)
            v[j] = H32[(long long)s[j] * 64 + lane];
        #pragma unroll
        for (int j = 0; j < 8; ++j) {
            float t = a_s[s[j]] + ad;
            t = t > 0.f ? t : NEG_SLOPE * t;
            float w = __expf(t);
            acc0 += w * bflo(v[j]);
            acc1 += w * bfhi(v[j]);
            wsum += w;
        }
    }
    for (; i < end; ++i) {
        int s = __builtin_amdgcn_readfirstlane(perm[i]);
        unsigned int v = H32[(long long)s * 64 + lane];
        float t = a_s[s] + ad;
        t = t > 0.f ? t : NEG_SLOPE * t;
        float w = __expf(t);
        acc0 += w * bflo(v); acc1 += w * bfhi(v);
        wsum += w;
    }
    float inv = (wsum > 0.f) ? __fdividef(1.f, wsum) : 0.f;  // deg-0 -> bias only
    float o0 = fmaxf(acc0 * inv + bias[2 * lane], 0.f);      // + b1, relu
    float o1 = fmaxf(acc1 * inv + bias[2 * lane + 1], 0.f);
    unsigned int pk = (unsigned int)f2bf(o0) | ((unsigned int)f2bf(o1) << 16);
    ((unsigned int*)out_bf)[(long long)wave * 64 + lane] = pk;
}

// ---------------------------------------------------------------------------
// Layer-2 aggregate (C=64): half-wave per edge, 4-deep unroll (8 rows in
// flight), cross-half shfl merge.
// ---------------------------------------------------------------------------
__launch_bounds__(256)
__global__ void k_agg64(const int* __restrict__ rowptr, const int* __restrict__ perm,
                        const float* __restrict__ a_s, const float* __restrict__ a_d,
                        const unsigned short* __restrict__ H, const float* __restrict__ bias,
                        float* __restrict__ out, int N) {
    int wave = (int)(((long long)blockIdx.x * 256 + threadIdx.x) >> 6);
    int lane = threadIdx.x & 63;
    if (wave >= N) return;
    int c = lane & 31, h = lane >> 5;  // half-wave id
    int beg = __builtin_amdgcn_readfirstlane(rowptr[wave]);
    int end = __builtin_amdgcn_readfirstlane(rowptr[wave + 1]);
    float ad = __uint_as_float(__builtin_amdgcn_readfirstlane(__float_as_uint(a_d[wave])));

    const unsigned int* H32 = (const unsigned int*)H;  // 32 uints/row
    float acc0 = 0.f, acc1 = 0.f, wsum = 0.f;
    int base = beg;
    for (; base + 8 <= end; base += 8) {
        int s[4];
        unsigned int v[4];
        #pragma unroll
        for (int j = 0; j < 4; ++j)
            s[j] = perm[base + h + 2 * j];
        #pragma unroll
        for (int j = 0; j < 4; ++j)
            v[j] = H32[(long long)s[j] * 32 + c];
        #pragma unroll
        for (int j = 0; j < 4; ++j) {
            float t = a_s[s[j]] + ad;
            t = t > 0.f ? t : NEG_SLOPE * t;
            float w = __expf(t);
            acc0 += w * bflo(v[j]);
            acc1 += w * bfhi(v[j]);
            wsum += w;
        }
    }
    for (int i = base + h; i < end; i += 2) {
        int s = perm[i];
        unsigned int v = H32[(long long)s * 32 + c];
        float t = a_s[s] + ad;
        t = t > 0.f ? t : NEG_SLOPE * t;
        float w = __expf(t);
        acc0 += w * bflo(v); acc1 += w * bfhi(v);
        wsum += w;
    }
    acc0 += __shfl_xor(acc0, 32);
    acc1 += __shfl_xor(acc1, 32);
    wsum += __shfl_xor(wsum, 32);
    if (h == 0) {
        float inv = (wsum > 0.f) ? __fdividef(1.f, wsum) : 0.f;
        float2 o;
        o.x = acc0 * inv + bias[2 * c];
        o.y = acc1 * inv + bias[2 * c + 1];
        *(float2*)(out + (long long)wave * 64 + 2 * c) = o;
    }
}

extern "C" void kernel_launch(void* const* d_in, const int* in_sizes, int n_in,
                              void* d_out, int out_size, void* d_ws, size_t ws_size,
                              hipStream_t stream) {
    const float* x   = (const float*)d_in[0];
    const int*   ei  = (const int*)d_in[1];
    const float* Ws1 = (const float*)d_in[2];
    const float* Wd1 = (const float*)d_in[3];
    const float* as1 = (const float*)d_in[4];
    const float* ad1 = (const float*)d_in[5];
    const float* b1  = (const float*)d_in[6];
    const float* Ws2 = (const float*)d_in[7];
    const float* Wd2 = (const float*)d_in[8];
    const float* as2 = (const float*)d_in[9];
    const float* ad2 = (const float*)d_in[10];
    const float* b2  = (const float*)d_in[11];
    float* out = (float*)d_out;

    const int N = in_sizes[0] / F_IN;   // 100000
    const int E = in_sizes[1] / 2;      // 1600000
    const int* srcs = ei;
    const int* dsts = ei + E;

    // Workspace (~60 MB). rank aliases x2bf (dead before k_agg128 writes it).
    unsigned short* hbuf = (unsigned short*)d_ws;              // N*128 bf16
    unsigned short* x2bf = hbuf + (size_t)N * 128;             // N*128 bf16
    int*   perm   = (int*)(x2bf + (size_t)N * 128);            // E (src only)
    float* a_s1   = (float*)(perm + E);
    float* a_d1   = a_s1 + N;
    float* a_s2   = a_d1 + N;
    float* a_d2   = a_s2 + N;
    int*   cnt    = (int*)(a_d2 + N);                          // N
    int*   rowptr = cnt + N;                                   // N+1 (pad to +4)
    int*   bsum   = rowptr + N + 4;                            // 64
    int*   bpre   = bsum + 64;                                 // 64
    unsigned short* w1hi = (unsigned short*)(bpre + 64);       // 16384 (swizzled)
    unsigned short* w1lo = w1hi + 16384;
    unsigned short* w2hi = w1lo + 16384;                       // 8192 (swizzled)
    unsigned short* w2lo = w2hi + 8192;
    float* vecs   = (float*)(w2lo + 8192);                     // 512
    int*   rank   = (int*)x2bf;                                // E (alias)

    const int nb = (N + SCAN_CHUNK - 1) / SCAN_CHUNK;

    // ---- prep (cnt zero + attention vecs + swizzled W hi/lo) ----
    k_prep<<<(N + 255) / 256, 256, 0, stream>>>(Ws1, Wd1, as1, ad1, Ws2, Wd2,
                                                as2, ad2, vecs, cnt,
                                                w1hi, w1lo, w2hi, w2lo, N);
    // ---- CSR build (once, reused by both layers) ----
    k_hist<<<(E + 255) / 256, 256, 0, stream>>>(dsts, cnt, rank, E);
    k_blocksum<<<nb, 256, 0, stream>>>(cnt, bsum, N);
    k_scan_bsum<<<1, 64, 0, stream>>>(bsum, bpre, nb, rowptr, N);
    k_scan_chunks<<<nb, 256, 0, stream>>>(cnt, bpre, rowptr, N);
    k_place<<<(E + 255) / 256, 256, 0, stream>>>(srcs, dsts, rowptr, rank, perm, E);

    // ---- Layer 1: fp32 X, split-bf16 MFMA ----
    k_gemm_mfma<128, false><<<(N + 127) / 128, 256, 0, stream>>>(
        x, w1hi, w1lo, vecs, vecs + 128, hbuf, a_s1, a_d1, N);
    k_agg128<<<(N + 3) / 4, 256, 0, stream>>>(
        rowptr, perm, a_s1, a_d1, hbuf, b1, x2bf, N);

    // ---- Layer 2: bf16 X (relu'd, b1 folded in by agg) ----
    k_gemm_mfma<64, true><<<(N + 127) / 128, 256, 0, stream>>>(
        x2bf, w2hi, w2lo, vecs + 256, vecs + 384, hbuf, a_s2, a_d2, N);
    k_agg64<<<(N + 3) / 4, 256, 0, stream>>>(
        rowptr, perm, a_s2, a_d2, hbuf, b2, out, N);
}